// Round 5
// baseline (18226.102 us; speedup 1.0000x reference)
//
#include <hip/hip_runtime.h>
#include <math.h>

#define BB 128
#define TT 256
#define TMEL 800
#define EE 512
#define HH 1024
#define MELD 128
#define VV 256

// ws offsets (float units)
#define OFF_PROJ  0u
#define OFF_T1    131072u
#define OFF_WR2   524288u
#define OFF_BB1   917504u
#define OFF_BB2   918016u
#define OFF_B2    918528u
#define OFF_W2C   922624u
#define OFF_BAR   5116928u
#define OFF_WENCR 5117440u
#define OFF_W2CR  8263168u
#define OFF_WHHDR 10360320u
#define OFF_WPGS  12457472u
#define OFF_H2B   12531200u
#define OFF_RING  20919808u   /* aliases conv scratch h1pb (dead after conv2) */

typedef __bf16 bfv8 __attribute__((ext_vector_type(8)));
typedef float f32x4 __attribute__((ext_vector_type(4)));

__device__ __forceinline__ unsigned short f2b(float f){
  union { float f; unsigned u; } v; v.f = f;
  unsigned u = v.u;
  return (unsigned short)((u + 0x7fffu + ((u>>16)&1u)) >> 16);
}
__device__ __forceinline__ float sigm(float x){ return 1.0f/(1.0f+expf(-x)); }

__device__ __forceinline__ f32x4 mfma16(bfv8 a, bfv8 b, f32x4 c){
  return __builtin_amdgcn_mfma_f32_16x16x32_bf16(a, b, c, 0, 0, 0);
}

// ---- fp32 precompute kernels ----

__global__ void k_proj(const float* __restrict__ emb, const float* __restrict__ W,
                       const float* __restrict__ bias, float* __restrict__ proj){
  __shared__ float er[EE];
  int v = blockIdx.x;
  for(int i=threadIdx.x;i<EE;i+=256) er[i]=emb[v*EE+i];
  __syncthreads();
  for(int e=threadIdx.x;e<EE;e+=256){
    const float* wr = W + e*EE;
    float acc=0.f;
    for(int k=0;k<EE;k+=4){
      float4 w4 = *(const float4*)(wr+k);
      acc += er[k]*w4.x + er[k+1]*w4.y + er[k+2]*w4.z + er[k+3]*w4.w;
    }
    proj[v*EE+e] = acc + bias[e];
  }
}

__global__ void k_t1(const float* __restrict__ proj, const float* __restrict__ W1,
                     const float* __restrict__ g1, float* __restrict__ T1){
  __shared__ float pr[EE];
  int v = blockIdx.x; int k3 = blockIdx.y;
  for(int i=threadIdx.x;i<EE;i+=256) pr[i]=proj[v*EE+i];
  __syncthreads();
  const float s = rsqrtf(1.f+1e-5f);
  for(int c=threadIdx.x;c<EE;c+=256){
    float acc=0.f;
    const float* w = W1 + c*EE*3 + k3;
    for(int ci=0;ci<EE;ci++) acc += pr[ci]*w[ci*3];
    T1[(v*3+k3)*EE+c] = g1[c]*s*acc;
  }
}

__global__ void k_wr2(const float* __restrict__ W2, const float* __restrict__ g2,
                      unsigned short* __restrict__ Wr){
  int idx = blockIdx.x*256+threadIdx.x;
  if(idx >= EE*3*EE) return;
  int c = idx/1536; int r = idx%1536; int k3 = r/EE; int ci = r%EE;
  const float s = rsqrtf(1.f+1e-5f);
  Wr[idx] = f2b(g2[c]*s*W2[(c*EE+ci)*3+k3]);
}

__global__ void k_bb(const float* __restrict__ b1,const float* __restrict__ g1,const float* __restrict__ be1,
                     const float* __restrict__ b2,const float* __restrict__ g2,const float* __restrict__ be2,
                     float* __restrict__ bb1, float* __restrict__ bb2){
  int c = threadIdx.x + blockIdx.x*256; if(c>=EE) return;
  const float s = rsqrtf(1.f+1e-5f);
  bb1[c] = g1[c]*s*b1[c] + be1[c];
  bb2[c] = g2[c]*s*b2[c] + be2[c];
}

__global__ void k_b2(const float* __restrict__ bd, const float* __restrict__ Wih,
                     const float* __restrict__ bp, float* __restrict__ b2){
  int j = blockIdx.x*256+threadIdx.x; if(j>=4096) return;
  float acc = bd[j];
  const float* w = Wih + j*MELD;
  for(int m=0;m<MELD;m++) acc += w[m]*bp[m];
  b2[j] = acc;
}

__global__ void k_w2c(const float* __restrict__ Whh, const float* __restrict__ Wih,
                      const float* __restrict__ Wp, float* __restrict__ W2c){
  __shared__ float wl[8][MELD];
  int j0 = blockIdx.x*8; int k = blockIdx.y*256 + threadIdx.x;
  for(int i=threadIdx.x;i<8*MELD;i+=256) wl[i/MELD][i%MELD] = Wih[(j0+i/MELD)*MELD + (i%MELD)];
  __syncthreads();
  float acc[8];
  #pragma unroll
  for(int jj=0;jj<8;jj++) acc[jj]=Whh[(j0+jj)*HH+k];
  for(int m=0;m<MELD;m++){
    float wp = Wp[m*HH+k];
    #pragma unroll
    for(int jj=0;jj<8;jj++) acc[jj] += wl[jj][m]*wp;
  }
  #pragma unroll
  for(int jj=0;jj<8;jj++) W2c[(j0+jj)*HH+k] = acc[jj];
}

// ---- fragment packing for the recurrence ----
// 256 WGs = 4 bg x 64 cg; 16 waves = gate g(0..3) x K-split kh(0..3)
// tile = cg*16 + wvi, wvi = g*4 + kh
// gate col j = g*1024 + cg*16 + (l&15)
// enc virtual K = 1536 (X 0..512 | h 512..1536), 12 kt per wave
__global__ void k_pack_enc2(const float* __restrict__ Wih, const float* __restrict__ Whh,
                            unsigned short* __restrict__ dst){
  int tile = blockIdx.x; // 0..1023
  int cg = tile>>4, wvi = tile&15, g = wvi>>2, kh = wvi&3;
  for(int i=threadIdx.x; i<12*64*8; i+=256){
    int kt = i>>9, l = (i>>3)&63, e = i&7;
    int j = g*HH + cg*16 + (l&15);
    int k = kh*384 + kt*32 + ((l>>4)<<3) + e;
    float v = (k<512)? Wih[(size_t)j*EE + k] : Whh[(size_t)j*HH + (k-512)];
    dst[((size_t)(tile*12 + kt)*64 + l)*8 + e] = f2b(v);
  }
}

// dec: K=1024, 8 kt per wave
__global__ void k_pack_dec2(const float* __restrict__ W, unsigned short* __restrict__ dst){
  int tile = blockIdx.x; // 0..1023
  int cg = tile>>4, wvi = tile&15, g = wvi>>2, kh = wvi&3;
  for(int i=threadIdx.x; i<8*64*8; i+=256){
    int kt = i>>9, l = (i>>3)&63, e = i&7;
    int j = g*HH + cg*16 + (l&15);
    int k = kh*256 + kt*32 + ((l>>4)<<3) + e;
    dst[((size_t)(tile*8 + kt)*64 + l)*8 + e] = f2b(W[(size_t)j*HH + k]);
  }
}

__global__ void k_pack_pg(const float* __restrict__ Wp, const float* __restrict__ Wg,
                          unsigned short* __restrict__ dst){
  int nt = blockIdx.x; // 0..8
  for(int i=threadIdx.x; i<32*64*8; i+=256){
    int kt = i>>9; int l = (i>>3)&63; int e = i&7;
    int n = nt*16 + (l&15);
    int k = ((l>>4)<<3) + kt*32 + e;
    float v = (n<MELD)? Wp[(size_t)n*HH+k] : (n==MELD? Wg[k] : 0.f);
    dst[((size_t)(nt*32 + kt)*64 + l)*8 + e] = f2b(v);
  }
}

// ---- conv path ----

__global__ void k_pad(unsigned short* __restrict__ h1pb){
  int idx = blockIdx.x*256+threadIdx.x;
  int c = idx & 511; int b = idx >> 9;
  h1pb[((size_t)b*258)*EE + c] = 0;
  h1pb[((size_t)b*258 + 257)*EE + c] = 0;
}

__global__ void k_conv1(const int* __restrict__ x, const float* __restrict__ T1,
                        const float* __restrict__ bb1, unsigned short* __restrict__ h1pb){
  int idx = blockIdx.x*256+threadIdx.x;
  int c = idx & 511; int bt = idx >> 9; int t = bt & 255; int b = bt >> 8;
  float acc = bb1[c];
  if(t > 0)    acc += T1[(size_t)(x[b*TT+t-1]*3+0)*EE+c];
               acc += T1[(size_t)(x[b*TT+t  ]*3+1)*EE+c];
  if(t < TT-1) acc += T1[(size_t)(x[b*TT+t+1]*3+2)*EE+c];
  h1pb[((size_t)b*258 + t + 1)*EE + c] = f2b(fmaxf(acc, 0.f));
}

template<int NKT>
__device__ __forceinline__ void mm_seg_stream(const unsigned short* A, int lda,
    const unsigned short* Wrow, f32x4& acc0, f32x4& acc1, int l, int wv){
  int r0 = wv*32 + (l&15);
  int k8 = (l>>4)*8;
  const unsigned short* a0 = A + (size_t)r0*lda + k8;
  const unsigned short* a1 = a0 + 16*lda;
  const unsigned short* wp = Wrow + k8;
  #pragma unroll
  for(int kt=0;kt<NKT;kt++){
    bfv8 bv = *(const bfv8*)(const void*)(wp + kt*32);
    acc0 = mfma16(*(const bfv8*)(const void*)(a0 + kt*32), bv, acc0);
    acc1 = mfma16(*(const bfv8*)(const void*)(a1 + kt*32), bv, acc1);
  }
}

__global__ __launch_bounds__(256,2) void k_conv2mm(const unsigned short* __restrict__ h1pb,
    const unsigned short* __restrict__ Wr2b, const float* __restrict__ bb2,
    unsigned short* __restrict__ h2b){
  int b = blockIdx.x;    // 0..127
  int th = blockIdx.y;   // 0..1
  int nt = blockIdx.z;   // 0..31
  int tid=threadIdx.x; int wv=tid>>6, l=tid&63;
  const unsigned short* A = h1pb + ((size_t)b*258 + th*128)*EE;
  const unsigned short* Wrow = Wr2b + (size_t)(nt*16+(l&15))*1536;
  f32x4 acc0={0,0,0,0}, acc1={0,0,0,0};
  mm_seg_stream<48>(A, EE, Wrow, acc0, acc1, l, wv);
  int rr=(l>>4)*4, cc=l&15;
  int n = nt*16+cc;
  float bias = bb2[n];
  #pragma unroll
  for(int mi=0;mi<2;mi++){
    f32x4 acc = mi?acc1:acc0;
    int tb = th*128 + wv*32 + mi*16 + rr;
    #pragma unroll
    for(int q=0;q<4;q++){
      float v = fmaxf(acc[q]+bias, 0.f);
      h2b[((size_t)(tb+q)*BB + b)*EE + n] = f2b(v);
    }
  }
}

// ---- group barrier (all relaxed; syncthreads drains vmcnt before arrive) ----
__device__ __forceinline__ void g_arrive(unsigned int* cnt, unsigned int* gen){
  __syncthreads();
  if(threadIdx.x == 0){
    unsigned int old = __hip_atomic_fetch_add(cnt, 1u, __ATOMIC_RELAXED, __HIP_MEMORY_SCOPE_AGENT);
    if(old == 63u){
      __hip_atomic_store(cnt, 0u, __ATOMIC_RELAXED, __HIP_MEMORY_SCOPE_AGENT);
      __hip_atomic_fetch_add(gen, 1u, __ATOMIC_RELAXED, __HIP_MEMORY_SCOPE_AGENT);
    }
  }
}
__device__ __forceinline__ void g_wait(unsigned int* gen, unsigned int target){
  if(threadIdx.x == 0){
    while(__hip_atomic_load(gen, __ATOMIC_RELAXED, __HIP_MEMORY_SCOPE_AGENT) < target)
      __builtin_amdgcn_s_sleep(1);
  }
  asm volatile("" ::: "memory");
  __syncthreads();
}

// stage 32 rows x 1024 h-cols of a ring slot into swizzled As at byte base
__device__ __forceinline__ void stage_h(char* As, const unsigned short* slotp,
                                        int basebyte, int bg, int tid){
  for(int i = tid; i < 8192; i += 1024){
    int r = i >> 8, c8 = i & 255;
    const unsigned long long* p =
      (const unsigned long long*)(slotp + (size_t)(bg*32+r)*HH + c8*4);
    unsigned long long v = __hip_atomic_load(p, __ATOMIC_RELAXED, __HIP_MEMORY_SCOPE_AGENT);
    *(unsigned long long*)(As + ((r*3072 + basebyte + c8*8) ^ ((r&7)<<4))) = v;
  }
}

// ---- persistent recurrence: 256 WGs x 1024 thr = 4 bg(32 rows) x 64 cg(16 h-cols) ----
__global__ __launch_bounds__(1024,1) void k_recur(
  const unsigned short* __restrict__ h2b, unsigned short* __restrict__ ring,
  const unsigned short* __restrict__ WencR, const unsigned short* __restrict__ W2cR,
  const unsigned short* __restrict__ WhhdR, const unsigned short* __restrict__ WpgS,
  const float* __restrict__ bhe, const float* __restrict__ bd, const float* __restrict__ b2,
  const float* __restrict__ bp, const float* __restrict__ bgp,
  unsigned int* __restrict__ bar,
  const int* __restrict__ tlen, const int* __restrict__ mlen,
  float* __restrict__ outmel, float* __restrict__ outgate)
{
  __shared__ __align__(16) char As[32*3072];   // 96 KB: X bytes 0..1024 | h 1024..3072 (enc); h 0..2048 (dec)
  __shared__ float Gs[4][32][68];              // K-split partial gates: 34.8 KB

  const int bid = blockIdx.x;
  const int bg = bid & 3, cg = bid >> 2;
  const int tid = threadIdx.x;
  const int wvi = tid >> 6, l = tid & 63;
  const int g = wvi >> 2, kh = wvi & 3;
  const int tile = cg*16 + wvi;
  unsigned int* cnt = bar + bg*32;
  unsigned int* gen = bar + 256 + bg*32;
  unsigned int ge = 1;

  const int fr = l & 15;
  const int swz = (fr & 7) << 4;
  const int rb0 = fr*3072;
  const int rb1 = (fr+16)*3072;
  const int kcol = (l>>4) << 4;   // byte offset of this lane's k8 within a kt block

  // lstm thread mapping (tid<256): row lr 0..31, col pair lc in WG's 16 cols
  const int lr = tid >> 3;
  const int lc = (tid & 7) * 2;
  const int hcol = cg*16 + lc;
  float cs0 = 0.f, cs1 = 0.f;
  unsigned int hp = 0u;
  int mylen = 0;
  if(tid < 256) mylen = tlen[bg*32 + lr];

  // zero enc h_0 (slot 100), own stripe
  if(tid < 256){
    unsigned int* p = (unsigned int*)
      (ring + (size_t)100*BB*HH + (size_t)(bg*32+lr)*HH + hcol);
    __hip_atomic_store(p, 0u, __ATOMIC_RELAXED, __HIP_MEMORY_SCOPE_AGENT);
  }
  g_arrive(cnt, gen);

  // ================= encoder: 256 steps, resident 12 frags/wave =================
  {
    bfv8 bfe[12];
    const unsigned short* wp = WencR + (size_t)tile*12*512 + (size_t)l*8;
    #pragma unroll
    for(int kt=0;kt<12;kt++) bfe[kt] = *(const bfv8*)(const void*)(wp + kt*512);

    float ei0=0,ei1=0,ef0=0,ef1=0,eg0=0,eg1=0,eo0=0,eo1=0;
    if(tid < 256){
      ei0=bhe[hcol];      ei1=bhe[hcol+1];
      ef0=bhe[HH+hcol];   ef1=bhe[HH+hcol+1];
      eg0=bhe[2*HH+hcol]; eg1=bhe[2*HH+hcol+1];
      eo0=bhe[3*HH+hcol]; eo1=bhe[3*HH+hcol+1];
    }

    #pragma unroll 1
    for(int t=0;t<TT;t++){
      // stage X_t (no dependency on h_t) into As bytes [0,1024) per row
      {
        const uint4* src = (const uint4*)(h2b + (size_t)(t*BB + bg*32)*EE);
        for(int i = tid; i < 2048; i += 1024){
          int r = i >> 6, c16 = i & 63;
          uint4 v = src[r*64 + c16];
          *(uint4*)(As + ((r*3072 + c16*16) ^ ((r&7)<<4))) = v;
        }
      }
      g_wait(gen, ge);   // h_t ready (also covers stage_x via its syncthreads)
      stage_h(As, ring + (size_t)(100 + (t&1))*BB*HH, 1024, bg, tid);
      __syncthreads();
      f32x4 acc0={0,0,0,0}, acc1={0,0,0,0};
      {
        const int kb = kh*768 + kcol;
        #pragma unroll
        for(int kt=0;kt<12;kt++){
          bfv8 a0 = *(const bfv8*)(const void*)(As + ((rb0 + kb + kt*64) ^ swz));
          bfv8 a1 = *(const bfv8*)(const void*)(As + ((rb1 + kb + kt*64) ^ swz));
          acc0 = mfma16(a0, bfe[kt], acc0);
          acc1 = mfma16(a1, bfe[kt], acc1);
        }
      }
      {
        int rr = (l>>4)*4;
        #pragma unroll
        for(int q=0;q<4;q++){
          Gs[kh][rr+q][g*16+fr]    = acc0[q];
          Gs[kh][16+rr+q][g*16+fr] = acc1[q];
        }
      }
      __syncthreads();
      if(tid < 256){
        float gi0 = Gs[0][lr][lc]   +Gs[1][lr][lc]   +Gs[2][lr][lc]   +Gs[3][lr][lc]    + ei0;
        float gi1 = Gs[0][lr][lc+1] +Gs[1][lr][lc+1] +Gs[2][lr][lc+1] +Gs[3][lr][lc+1]  + ei1;
        float gf0 = Gs[0][lr][16+lc]+Gs[1][lr][16+lc]+Gs[2][lr][16+lc]+Gs[3][lr][16+lc] + ef0;
        float gf1 = Gs[0][lr][17+lc]+Gs[1][lr][17+lc]+Gs[2][lr][17+lc]+Gs[3][lr][17+lc] + ef1;
        float gg0 = Gs[0][lr][32+lc]+Gs[1][lr][32+lc]+Gs[2][lr][32+lc]+Gs[3][lr][32+lc] + eg0;
        float gg1 = Gs[0][lr][33+lc]+Gs[1][lr][33+lc]+Gs[2][lr][33+lc]+Gs[3][lr][33+lc] + eg1;
        float go0 = Gs[0][lr][48+lc]+Gs[1][lr][48+lc]+Gs[2][lr][48+lc]+Gs[3][lr][48+lc] + eo0;
        float go1 = Gs[0][lr][49+lc]+Gs[1][lr][49+lc]+Gs[2][lr][49+lc]+Gs[3][lr][49+lc] + eo1;
        float c20 = sigm(gf0)*cs0 + sigm(gi0)*tanhf(gg0);
        float c21 = sigm(gf1)*cs1 + sigm(gi1)*tanhf(gg1);
        float h20 = sigm(go0)*tanhf(c20);
        float h21 = sigm(go1)*tanhf(c21);
        if(t < mylen){
          cs0 = c20; cs1 = c21;
          hp = (unsigned)f2b(h20) | ((unsigned)f2b(h21)<<16);
        }
        unsigned short* outslot = (t==TT-1) ? (ring + (size_t)99*BB*HH)
                                            : (ring + (size_t)(100 + ((t+1)&1))*BB*HH);
        __hip_atomic_store((unsigned int*)(outslot + (size_t)(bg*32+lr)*HH + hcol), hp,
                           __ATOMIC_RELAXED, __HIP_MEMORY_SCOPE_AGENT);
      }
      g_arrive(cnt, gen); ge++;
    }
  }

  // ================= decoder: 800 steps, resident 8 frags/wave =================
  {
    bfv8 bfd[8];
    const unsigned short* wp = W2cR + (size_t)tile*8*512 + (size_t)l*8;
    #pragma unroll
    for(int kt=0;kt<8;kt++) bfd[kt] = *(const bfv8*)(const void*)(wp + kt*512);

    float di0=0,di1=0,df0=0,df1=0,dg0=0,dg1=0,do0=0,do1=0;
    if(tid < 256){
      di0=b2[hcol];      di1=b2[hcol+1];
      df0=b2[HH+hcol];   df1=b2[HH+hcol+1];
      dg0=b2[2*HH+hcol]; dg1=b2[2*HH+hcol+1];
      do0=b2[3*HH+hcol]; do1=b2[3*HH+hcol+1];
    }

    #pragma unroll 1
    for(int t=0;t<TMEL;t++){
      g_wait(gen, ge);
      const unsigned short* slotin = (t==0) ? ring + (size_t)99*BB*HH
                                            : ring + (size_t)((t-1)%100)*BB*HH;
      stage_h(As, slotin, 0, bg, tid);
      __syncthreads();
      f32x4 acc0={0,0,0,0}, acc1={0,0,0,0};
      const int kb = kh*512 + kcol;
      if(t == 0){
        const unsigned short* wps = WhhdR + (size_t)tile*8*512 + (size_t)l*8;
        #pragma unroll
        for(int kt=0;kt<8;kt++){
          bfv8 wf = *(const bfv8*)(const void*)(wps + kt*512);
          bfv8 a0 = *(const bfv8*)(const void*)(As + ((rb0 + kb + kt*64) ^ swz));
          bfv8 a1 = *(const bfv8*)(const void*)(As + ((rb1 + kb + kt*64) ^ swz));
          acc0 = mfma16(a0, wf, acc0);
          acc1 = mfma16(a1, wf, acc1);
        }
      } else {
        #pragma unroll
        for(int kt=0;kt<8;kt++){
          bfv8 a0 = *(const bfv8*)(const void*)(As + ((rb0 + kb + kt*64) ^ swz));
          bfv8 a1 = *(const bfv8*)(const void*)(As + ((rb1 + kb + kt*64) ^ swz));
          acc0 = mfma16(a0, bfd[kt], acc0);
          acc1 = mfma16(a1, bfd[kt], acc1);
        }
      }
      {
        int rr = (l>>4)*4;
        #pragma unroll
        for(int q=0;q<4;q++){
          Gs[kh][rr+q][g*16+fr]    = acc0[q];
          Gs[kh][16+rr+q][g*16+fr] = acc1[q];
        }
      }
      __syncthreads();
      if(tid < 256){
        float bi0=di0,bi1=di1,bff0=df0,bff1=df1,bgg0=dg0,bgg1=dg1,bo0=do0,bo1=do1;
        if(t==0){
          bi0=bd[hcol];       bi1=bd[hcol+1];
          bff0=bd[HH+hcol];   bff1=bd[HH+hcol+1];
          bgg0=bd[2*HH+hcol]; bgg1=bd[2*HH+hcol+1];
          bo0=bd[3*HH+hcol];  bo1=bd[3*HH+hcol+1];
        }
        float gi0 = Gs[0][lr][lc]   +Gs[1][lr][lc]   +Gs[2][lr][lc]   +Gs[3][lr][lc]    + bi0;
        float gi1 = Gs[0][lr][lc+1] +Gs[1][lr][lc+1] +Gs[2][lr][lc+1] +Gs[3][lr][lc+1]  + bi1;
        float gf0 = Gs[0][lr][16+lc]+Gs[1][lr][16+lc]+Gs[2][lr][16+lc]+Gs[3][lr][16+lc] + bff0;
        float gf1 = Gs[0][lr][17+lc]+Gs[1][lr][17+lc]+Gs[2][lr][17+lc]+Gs[3][lr][17+lc] + bff1;
        float gg0 = Gs[0][lr][32+lc]+Gs[1][lr][32+lc]+Gs[2][lr][32+lc]+Gs[3][lr][32+lc] + bgg0;
        float gg1 = Gs[0][lr][33+lc]+Gs[1][lr][33+lc]+Gs[2][lr][33+lc]+Gs[3][lr][33+lc] + bgg1;
        float go0 = Gs[0][lr][48+lc]+Gs[1][lr][48+lc]+Gs[2][lr][48+lc]+Gs[3][lr][48+lc] + bo0;
        float go1 = Gs[0][lr][49+lc]+Gs[1][lr][49+lc]+Gs[2][lr][49+lc]+Gs[3][lr][49+lc] + bo1;
        float c20 = sigm(gf0)*cs0 + sigm(gi0)*tanhf(gg0);
        float c21 = sigm(gf1)*cs1 + sigm(gi1)*tanhf(gg1);
        cs0 = c20; cs1 = c21;
        float h20 = sigm(go0)*tanhf(c20);
        float h21 = sigm(go1)*tanhf(c21);
        unsigned int hn = (unsigned)f2b(h20) | ((unsigned)f2b(h21)<<16);
        unsigned short* outslot = ring + (size_t)(t%100)*BB*HH;
        __hip_atomic_store((unsigned int*)(outslot + (size_t)(bg*32+lr)*HH + hcol), hn,
                           __ATOMIC_RELAXED, __HIP_MEMORY_SCOPE_AGENT);
      }
      g_arrive(cnt, gen); ge++;

      if((t%100)==99){
        g_wait(gen, ge);   // all 100 slots final
        int tbase = t - 99;
        #pragma unroll 1
        for(int pass=0; pass<2; pass++){
          int s = cg + pass*64;
          if(s < 100){
            stage_h(As, ring + (size_t)s*BB*HH, 0, bg, tid);
            __syncthreads();
            if(wvi <= 8){
              int nt = wvi;
              const unsigned short* wsrc = WpgS + (size_t)nt*32*512 + (size_t)l*8;
              f32x4 ac0={0,0,0,0}, ac1={0,0,0,0};
              #pragma unroll
              for(int kt=0;kt<32;kt++){
                bfv8 wf = *(const bfv8*)(const void*)(wsrc + kt*512);
                bfv8 a0 = *(const bfv8*)(const void*)(As + ((rb0 + kcol + kt*64) ^ swz));
                bfv8 a1 = *(const bfv8*)(const void*)(As + ((rb1 + kcol + kt*64) ^ swz));
                ac0 = mfma16(a0, wf, ac0);
                ac1 = mfma16(a1, wf, ac1);
              }
              int tout = tbase + s;
              int n = nt*16 + fr;
              #pragma unroll
              for(int mi=0;mi<2;mi++){
                f32x4 ac = mi ? ac1 : ac0;
                #pragma unroll
                for(int q=0;q<4;q++){
                  int b = bg*32 + mi*16 + (l>>4)*4 + q;
                  bool msk = tout > mlen[b];
                  if(n < MELD)
                    outmel[((size_t)b*TMEL + tout)*MELD + n] = msk ? 0.f : ac[q]+bp[n];
                  else if(n == MELD)
                    outgate[(size_t)b*TMEL + tout] = msk ? 1000.f : ac[q]+bgp[0];
                }
              }
            }
          }
          __syncthreads();
        }
        g_arrive(cnt, gen); ge++;
      }
    }
  }
}

__global__ void k_mask(const int* __restrict__ mlen, float* __restrict__ om){
  int idx=blockIdx.x*256+threadIdx.x; if(idx>=BB*TMEL) return;
  int b=idx/TMEL, t=idx%TMEL;
  om[idx] = (t > mlen[b]) ? 1.f : 0.f;
}

extern "C" void kernel_launch(void* const* d_in, const int* in_sizes, int n_in,
                              void* d_out, int out_size, void* d_ws, size_t ws_size,
                              hipStream_t stream){
  (void)in_sizes; (void)n_in; (void)out_size; (void)ws_size;
  const int*   x    = (const int*)d_in[0];
  const int*   tlen = (const int*)d_in[1];
  const int*   mlen = (const int*)d_in[3];
  const float* emb  = (const float*)d_in[4];
  const float* elW  = (const float*)d_in[5];
  const float* elb  = (const float*)d_in[6];
  const float* c1W  = (const float*)d_in[7];
  const float* c1b  = (const float*)d_in[8];
  const float* g1   = (const float*)d_in[9];
  const float* be1  = (const float*)d_in[10];
  const float* c2W  = (const float*)d_in[11];
  const float* c2b  = (const float*)d_in[12];
  const float* g2   = (const float*)d_in[13];
  const float* be2  = (const float*)d_in[14];
  const float* Wihe = (const float*)d_in[15];
  const float* Whhe = (const float*)d_in[16];
  const float* bhe  = (const float*)d_in[17];
  const float* Wihd = (const float*)d_in[18];
  const float* Whhd = (const float*)d_in[19];
  const float* bhd  = (const float*)d_in[20];
  const float* Wp   = (const float*)d_in[21];
  const float* bp   = (const float*)d_in[22];
  const float* Wg   = (const float*)d_in[23];
  const float* bg   = (const float*)d_in[24];

  float* ws = (float*)d_ws;
  float* proj = ws + OFF_PROJ;
  float* T1   = ws + OFF_T1;
  unsigned short* Wr2b = (unsigned short*)(ws + OFF_WR2);
  float* bb1 = ws + OFF_BB1;
  float* bb2 = ws + OFF_BB2;
  float* b2  = ws + OFF_B2;
  float* W2c = ws + OFF_W2C;
  unsigned int* bar = (unsigned int*)(ws + OFF_BAR);
  unsigned short* WencR = (unsigned short*)(ws + OFF_WENCR);
  unsigned short* W2cR  = (unsigned short*)(ws + OFF_W2CR);
  unsigned short* WhhdR = (unsigned short*)(ws + OFF_WHHDR);
  unsigned short* WpgS  = (unsigned short*)(ws + OFF_WPGS);
  unsigned short* h2b   = (unsigned short*)(ws + OFF_H2B);
  unsigned short* h1pb  = (unsigned short*)(ws + OFF_RING); // conv scratch
  unsigned short* ring  = (unsigned short*)(ws + OFF_RING); // alias after conv2

  float* outmel  = (float*)d_out;
  float* outgate = outmel + (size_t)BB*TMEL*MELD;
  float* outmask = outgate + (size_t)BB*TMEL;

  hipMemsetAsync(bar, 0, 2048, stream);

  k_proj<<<VV,256,0,stream>>>(emb, elW, elb, proj);
  k_t1<<<dim3(VV,3),256,0,stream>>>(proj, c1W, g1, T1);
  k_wr2<<<(EE*3*EE+255)/256,256,0,stream>>>(c2W, g2, Wr2b);
  k_bb<<<2,256,0,stream>>>(c1b,g1,be1,c2b,g2,be2,bb1,bb2);
  k_b2<<<16,256,0,stream>>>(bhd, Wihd, bp, b2);
  k_w2c<<<dim3(4096/8,HH/256),256,0,stream>>>(Whhd, Wihd, Wp, W2c);
  k_pack_enc2<<<1024,256,0,stream>>>(Wihe, Whhe, WencR);
  k_pack_dec2<<<1024,256,0,stream>>>(W2c, W2cR);
  k_pack_dec2<<<1024,256,0,stream>>>(Whhd, WhhdR);
  k_pack_pg<<<9,256,0,stream>>>(Wp, Wg, WpgS);
  k_pad<<<256,256,0,stream>>>(h1pb);
  k_conv1<<<65536,256,0,stream>>>(x, T1, bb1, h1pb);
  k_conv2mm<<<dim3(BB,2,32),256,0,stream>>>(h1pb, Wr2b, bb2, h2b);

  void* kargs[] = {
    (void*)&h2b, (void*)&ring, (void*)&WencR, (void*)&W2cR, (void*)&WhhdR, (void*)&WpgS,
    (void*)&bhe, (void*)&bhd, (void*)&b2, (void*)&bp, (void*)&bg,
    (void*)&bar, (void*)&tlen, (void*)&mlen, (void*)&outmel, (void*)&outgate
  };
  hipLaunchCooperativeKernel((void*)k_recur, dim3(256), dim3(1024), kargs, 0u, stream);

  k_mask<<<(BB*TMEL+255)/256,256,0,stream>>>(mlen, outmask);
}

// Round 6
// 14062.115 us; speedup vs baseline: 1.2961x; 1.2961x over previous
//
#include <hip/hip_runtime.h>
#include <math.h>

#define BB 128
#define TT 256
#define TMEL 800
#define EE 512
#define HH 1024
#define MELD 128
#define VV 256

// ws offsets (float units)
#define OFF_PROJ  0u
#define OFF_T1    131072u
#define OFF_WR2   524288u
#define OFF_BB1   1310720u
#define OFF_BB2   1311232u
#define OFF_B2    1311744u
#define OFF_W2C   1315840u
#define OFF_BAR   5510144u
#define OFF_WENCR 5522688u
#define OFF_WIHS  7619840u
#define OFF_W2CR  8668416u
#define OFF_WHHDS 10765568u
#define OFF_WPGS  12862720u
#define OFF_H2B   12936448u
#define OFF_RING  21325056u   /* aliases h1pb (dead after conv2) */

typedef __bf16 bfv8 __attribute__((ext_vector_type(8)));
typedef float f32x4 __attribute__((ext_vector_type(4)));

__device__ __forceinline__ unsigned short f2b(float f){
  union { float f; unsigned u; } v; v.f = f;
  unsigned u = v.u;
  return (unsigned short)((u + 0x7fffu + ((u>>16)&1u)) >> 16);
}
__device__ __forceinline__ float sigm(float x){ return 1.0f/(1.0f+expf(-x)); }

__device__ __forceinline__ f32x4 mfma16(bfv8 a, bfv8 b, f32x4 c){
  return __builtin_amdgcn_mfma_f32_16x16x32_bf16(a, b, c, 0, 0, 0);
}

// ---- fp32 precompute kernels ----

__global__ void k_proj(const float* __restrict__ emb, const float* __restrict__ W,
                       const float* __restrict__ bias, float* __restrict__ proj){
  __shared__ float er[EE];
  int v = blockIdx.x;
  for(int i=threadIdx.x;i<EE;i+=256) er[i]=emb[v*EE+i];
  __syncthreads();
  for(int e=threadIdx.x;e<EE;e+=256){
    const float* wr = W + e*EE;
    float acc=0.f;
    for(int k=0;k<EE;k+=4){
      float4 w4 = *(const float4*)(wr+k);
      acc += er[k]*w4.x + er[k+1]*w4.y + er[k+2]*w4.z + er[k+3]*w4.w;
    }
    proj[v*EE+e] = acc + bias[e];
  }
}

__global__ void k_t1(const float* __restrict__ proj, const float* __restrict__ W1,
                     const float* __restrict__ g1, float* __restrict__ T1){
  __shared__ float pr[EE];
  int v = blockIdx.x; int k3 = blockIdx.y;
  for(int i=threadIdx.x;i<EE;i+=256) pr[i]=proj[v*EE+i];
  __syncthreads();
  const float s = rsqrtf(1.f+1e-5f);
  for(int c=threadIdx.x;c<EE;c+=256){
    float acc=0.f;
    const float* w = W1 + c*EE*3 + k3;
    for(int ci=0;ci<EE;ci++) acc += pr[ci]*w[ci*3];
    T1[(v*3+k3)*EE+c] = g1[c]*s*acc;
  }
}

__global__ void k_wr2(const float* __restrict__ W2, const float* __restrict__ g2,
                      unsigned short* __restrict__ Wr){
  int idx = blockIdx.x*256+threadIdx.x;
  if(idx >= EE*3*EE) return;
  int c = idx/1536; int r = idx%1536; int k3 = r/EE; int ci = r%EE;
  const float s = rsqrtf(1.f+1e-5f);
  Wr[idx] = f2b(g2[c]*s*W2[(c*EE+ci)*3+k3]);
}

__global__ void k_bb(const float* __restrict__ b1,const float* __restrict__ g1,const float* __restrict__ be1,
                     const float* __restrict__ b2,const float* __restrict__ g2,const float* __restrict__ be2,
                     float* __restrict__ bb1, float* __restrict__ bb2){
  int c = threadIdx.x + blockIdx.x*256; if(c>=EE) return;
  const float s = rsqrtf(1.f+1e-5f);
  bb1[c] = g1[c]*s*b1[c] + be1[c];
  bb2[c] = g2[c]*s*b2[c] + be2[c];
}

__global__ void k_b2(const float* __restrict__ bd, const float* __restrict__ Wih,
                     const float* __restrict__ bp, float* __restrict__ b2){
  int j = blockIdx.x*256+threadIdx.x; if(j>=4096) return;
  float acc = bd[j];
  const float* w = Wih + j*MELD;
  for(int m=0;m<MELD;m++) acc += w[m]*bp[m];
  b2[j] = acc;
}

__global__ void k_w2c(const float* __restrict__ Whh, const float* __restrict__ Wih,
                      const float* __restrict__ Wp, float* __restrict__ W2c){
  __shared__ float wl[8][MELD];
  int j0 = blockIdx.x*8; int k = blockIdx.y*256 + threadIdx.x;
  for(int i=threadIdx.x;i<8*MELD;i+=256) wl[i/MELD][i%MELD] = Wih[(j0+i/MELD)*MELD + (i%MELD)];
  __syncthreads();
  float acc[8];
  #pragma unroll
  for(int jj=0;jj<8;jj++) acc[jj]=Whh[(j0+jj)*HH+k];
  for(int m=0;m<MELD;m++){
    float wp = Wp[m*HH+k];
    #pragma unroll
    for(int jj=0;jj<8;jj++) acc[jj] += wl[jj][m]*wp;
  }
  #pragma unroll
  for(int jj=0;jj<8;jj++) W2c[(j0+jj)*HH+k] = acc[jj];
}

// ---- fragment packing ----
__global__ void k_pack(const float* __restrict__ src, unsigned short* __restrict__ dst,
                       int NKT, int K){
  int tile = blockIdx.x;
  int cg = tile>>3, wv = tile&7;
  int tot = NKT*64*8;
  for(int i=threadIdx.x; i<tot; i+=256){
    int kt = i>>9; int l = (i>>3)&63; int e = i&7;
    int j = (wv>>1)*1024 + cg*32 + (wv&1)*16 + (l&15);
    int k = ((l>>4)<<3) + kt*32 + e;
    dst[((size_t)(tile*NKT + kt)*64 + l)*8 + e] = f2b(src[(size_t)j*K + k]);
  }
}

__global__ void k_pack_pg(const float* __restrict__ Wp, const float* __restrict__ Wg,
                          unsigned short* __restrict__ dst){
  int nt = blockIdx.x; // 0..8
  for(int i=threadIdx.x; i<32*64*8; i+=256){
    int kt = i>>9; int l = (i>>3)&63; int e = i&7;
    int n = nt*16 + (l&15);
    int k = ((l>>4)<<3) + kt*32 + e;
    float v = (n<MELD)? Wp[(size_t)n*HH+k] : (n==MELD? Wg[k] : 0.f);
    dst[((size_t)(nt*32 + kt)*64 + l)*8 + e] = f2b(v);
  }
}

// ---- conv path ----

__global__ void k_pad(unsigned short* __restrict__ h1pb){
  int idx = blockIdx.x*256+threadIdx.x;
  int c = idx & 511; int b = idx >> 9;
  h1pb[((size_t)b*258)*EE + c] = 0;
  h1pb[((size_t)b*258 + 257)*EE + c] = 0;
}

__global__ void k_conv1(const int* __restrict__ x, const float* __restrict__ T1,
                        const float* __restrict__ bb1, unsigned short* __restrict__ h1pb){
  int idx = blockIdx.x*256+threadIdx.x;
  int c = idx & 511; int bt = idx >> 9; int t = bt & 255; int b = bt >> 8;
  float acc = bb1[c];
  if(t > 0)    acc += T1[(size_t)(x[b*TT+t-1]*3+0)*EE+c];
               acc += T1[(size_t)(x[b*TT+t  ]*3+1)*EE+c];
  if(t < TT-1) acc += T1[(size_t)(x[b*TT+t+1]*3+2)*EE+c];
  h1pb[((size_t)b*258 + t + 1)*EE + c] = f2b(fmaxf(acc, 0.f));
}

template<int NKT>
__device__ __forceinline__ void mm_seg_stream(const unsigned short* A, int lda,
    const unsigned short* Wrow, f32x4& acc0, f32x4& acc1, int l, int wv){
  int r0 = wv*32 + (l&15);
  int k8 = (l>>4)*8;
  const unsigned short* a0 = A + (size_t)r0*lda + k8;
  const unsigned short* a1 = a0 + 16*lda;
  const unsigned short* wp = Wrow + k8;
  #pragma unroll
  for(int kt=0;kt<NKT;kt++){
    bfv8 bv = *(const bfv8*)(const void*)(wp + kt*32);
    acc0 = mfma16(*(const bfv8*)(const void*)(a0 + kt*32), bv, acc0);
    acc1 = mfma16(*(const bfv8*)(const void*)(a1 + kt*32), bv, acc1);
  }
}

__global__ __launch_bounds__(256,2) void k_conv2mm(const unsigned short* __restrict__ h1pb,
    const unsigned short* __restrict__ Wr2b, const float* __restrict__ bb2,
    unsigned short* __restrict__ h2b){
  int b = blockIdx.x;    // 0..127
  int th = blockIdx.y;   // 0..1
  int nt = blockIdx.z;   // 0..31
  int tid=threadIdx.x; int wv=tid>>6, l=tid&63;
  const unsigned short* A = h1pb + ((size_t)b*258 + th*128)*EE;
  const unsigned short* Wrow = Wr2b + (size_t)(nt*16+(l&15))*1536;
  f32x4 acc0={0,0,0,0}, acc1={0,0,0,0};
  mm_seg_stream<48>(A, EE, Wrow, acc0, acc1, l, wv);
  int rr=(l>>4)*4, cc=l&15;
  int n = nt*16+cc;
  float bias = bb2[n];
  #pragma unroll
  for(int mi=0;mi<2;mi++){
    f32x4 acc = mi?acc1:acc0;
    int tb = th*128 + wv*32 + mi*16 + rr;
    #pragma unroll
    for(int q=0;q<4;q++){
      float v = fmaxf(acc[q]+bias, 0.f);
      h2b[((size_t)(tb+q)*BB + b)*EE + n] = f2b(v);
    }
  }
}

// ---- group barrier: all relaxed (no buffer_inv/wbl2). __syncthreads drains
// vmcnt per wave before the arrive, so agent-scope UC h-stores are acked at
// the coherence point before gen increments; consumers re-load via UC. ----
__device__ __forceinline__ void g_arrive(unsigned int* cnt, unsigned int* gen){
  __syncthreads();
  if(threadIdx.x == 0){
    unsigned int old = __hip_atomic_fetch_add(cnt, 1u, __ATOMIC_RELAXED, __HIP_MEMORY_SCOPE_AGENT);
    if(old == 31u){
      __hip_atomic_store(cnt, 0u, __ATOMIC_RELAXED, __HIP_MEMORY_SCOPE_AGENT);
      __hip_atomic_fetch_add(gen, 1u, __ATOMIC_RELAXED, __HIP_MEMORY_SCOPE_AGENT);
    }
  }
}
__device__ __forceinline__ void g_wait(unsigned int* gen, unsigned int target){
  if(threadIdx.x == 0){
    while(__hip_atomic_load(gen, __ATOMIC_RELAXED, __HIP_MEMORY_SCOPE_AGENT) < target)
      __builtin_amdgcn_s_sleep(1);
  }
  asm volatile("" ::: "memory");
  __syncthreads();
}

// stage 16 rows x 1024 cols of a ring slot into swizzled LDS
__device__ __forceinline__ void stage_h(unsigned short* hs, const unsigned short* slotp,
                                        int bg, int tid){
  for(int i = tid; i < 4096; i += 512){
    int r = i >> 8, c8 = i & 255;
    const unsigned long long* p =
      (const unsigned long long*)(slotp + (size_t)(bg*16+r)*HH + c8*4);
    unsigned long long v = __hip_atomic_load(p, __ATOMIC_RELAXED, __HIP_MEMORY_SCOPE_AGENT);
    *(unsigned long long*)((char*)hs + ((r*2048 + c8*8) ^ ((r&7)<<4))) = v;
  }
}

// ---- persistent recurrence: 256 WGs = 8 batch-groups x 32 col-groups.
// XCD-aware mapping: bg = bid>>5, cg = bid&31. Under round-robin dispatch,
// XCD x hosts cgs {x, x+8, x+16, x+24} for ALL 8 bgs -> per-XCD weight
// working set = 4 cgs x 256/384 KB = 1/1.5 MB << 4 MB L2 -> weights stay
// L2-resident across steps and the 8x bg duplication hits L2, not L3. ----
__global__ __launch_bounds__(512,2) void k_recur(
  const unsigned short* __restrict__ h2b, unsigned short* __restrict__ ring,
  const unsigned short* __restrict__ WencR, const unsigned short* __restrict__ WihS,
  const unsigned short* __restrict__ W2cR, const unsigned short* __restrict__ WhhdS,
  const unsigned short* __restrict__ WpgS,
  const float* __restrict__ bhe, const float* __restrict__ bd, const float* __restrict__ b2,
  const float* __restrict__ bp, const float* __restrict__ bgp,
  unsigned int* __restrict__ bar,
  const int* __restrict__ tlen, const int* __restrict__ mlen,
  float* __restrict__ outmel, float* __restrict__ outgate)
{
  __shared__ __align__(16) unsigned short hs[16*1024];  // 32KB
  __shared__ __align__(16) unsigned short Xs[16*512];   // 16KB
  __shared__ float Gs[16][132];

  const int bid = blockIdx.x;
  const int bg = bid >> 5, cg = bid & 31;   // XCD-slice mapping (perf only)
  const int tid = threadIdx.x;
  const int wvi = tid >> 6, l = tid & 63;
  const int tile = cg*8 + wvi;
  unsigned int* cnt = bar + bg*32;
  unsigned int* gen = bar + 256 + bg*32;
  unsigned int ge = 1;

  const int fr = l & 15;
  const int hswz = (fr & 7) << 4;
  const int hbase = fr*2048 + ((l>>4)<<4);
  const int xbase = fr*1024 + ((l>>4)<<4);

  const int lr = tid >> 4;
  const int lc = (tid & 15) * 2;
  const int hcol = cg*32 + lc;
  float cs0 = 0.f, cs1 = 0.f;
  unsigned int hp = 0u;
  int mylen = 0;
  if(tid < 256) mylen = tlen[bg*16 + lr];

  // zero enc h_0 (slot 100)
  if(tid < 128){
    int r = tid >> 3, c4 = (tid & 7) * 4;
    unsigned long long* p = (unsigned long long*)
      (ring + (size_t)100*BB*HH + (size_t)(bg*16+r)*HH + cg*32 + c4);
    __hip_atomic_store(p, 0ull, __ATOMIC_RELAXED, __HIP_MEMORY_SCOPE_AGENT);
  }
  g_arrive(cnt, gen);

  bfv8 bf[32];

  // ================= encoder: 256 steps =================
  #pragma unroll 1
  for(int kt=0;kt<32;kt++)
    bf[kt] = *(const bfv8*)(const void*)(WencR + ((size_t)(tile*32+kt)*64 + l)*8);

  float ei0=0,ei1=0,ef0=0,ef1=0,eg0=0,eg1=0,eo0=0,eo1=0;
  if(tid < 256){
    ei0=bhe[hcol];      ei1=bhe[hcol+1];
    ef0=bhe[HH+hcol];   ef1=bhe[HH+hcol+1];
    eg0=bhe[2*HH+hcol]; eg1=bhe[2*HH+hcol+1];
    eo0=bhe[3*HH+hcol]; eo1=bhe[3*HH+hcol+1];
  }

  #pragma unroll 1
  for(int t=0;t<TT;t++){
    {
      const uint4* src = (const uint4*)(h2b + (size_t)(t*BB + bg*16)*EE);
      for(int i = tid; i < 1024; i += 512){
        int r = i >> 6, c16 = i & 63;
        uint4 v = src[r*64 + c16];
        *(uint4*)((char*)Xs + ((r*1024 + c16*16) ^ ((r&7)<<4))) = v;
      }
    }
    __syncthreads();
    f32x4 acc = {0.f,0.f,0.f,0.f};
    {
      const unsigned short* wsrc = WihS + (size_t)tile*16*64*8;
      #pragma unroll
      for(int kt=0;kt<16;kt++){
        bfv8 wf = *(const bfv8*)(const void*)(wsrc + ((size_t)kt*64 + l)*8);
        bfv8 xv = *(const bfv8*)(const void*)((const char*)Xs + ((xbase + kt*64) ^ hswz));
        acc = mfma16(xv, wf, acc);
      }
    }
    g_wait(gen, ge);   // h_t ready
    stage_h(hs, ring + (size_t)(100 + (t&1))*BB*HH, bg, tid);
    __syncthreads();
    #pragma unroll
    for(int kt=0;kt<32;kt++){
      bfv8 hv = *(const bfv8*)(const void*)((const char*)hs + ((hbase + kt*64) ^ hswz));
      acc = mfma16(hv, bf[kt], acc);
    }
    {
      int rr = (l>>4)*4;
      #pragma unroll
      for(int q=0;q<4;q++) Gs[rr+q][wvi*16 + fr] = acc[q];
    }
    __syncthreads();
    if(tid < 256){
      float gi0 = Gs[lr][lc]    + ei0, gi1 = Gs[lr][lc+1] + ei1;
      float gf0 = Gs[lr][32+lc] + ef0, gf1 = Gs[lr][33+lc] + ef1;
      float gg0 = Gs[lr][64+lc] + eg0, gg1 = Gs[lr][65+lc] + eg1;
      float go0 = Gs[lr][96+lc] + eo0, go1 = Gs[lr][97+lc] + eo1;
      float c20 = sigm(gf0)*cs0 + sigm(gi0)*tanhf(gg0);
      float c21 = sigm(gf1)*cs1 + sigm(gi1)*tanhf(gg1);
      float h20 = sigm(go0)*tanhf(c20);
      float h21 = sigm(go1)*tanhf(c21);
      if(t < mylen){
        cs0 = c20; cs1 = c21;
        hp = (unsigned)f2b(h20) | ((unsigned)f2b(h21)<<16);
      }
      unsigned short* outslot = (t==TT-1) ? (ring + (size_t)99*BB*HH)
                                          : (ring + (size_t)(100 + ((t+1)&1))*BB*HH);
      __hip_atomic_store((unsigned int*)(outslot + (size_t)(bg*16+lr)*HH + hcol), hp,
                         __ATOMIC_RELAXED, __HIP_MEMORY_SCOPE_AGENT);
    }
    g_arrive(cnt, gen); ge++;
  }

  // ================= decoder: 800 steps =================
  #pragma unroll 1
  for(int kt=0;kt<32;kt++)
    bf[kt] = *(const bfv8*)(const void*)(W2cR + ((size_t)(tile*32+kt)*64 + l)*8);

  float di0=0,di1=0,df0=0,df1=0,dg0=0,dg1=0,do0=0,do1=0;
  if(tid < 256){
    di0=b2[hcol];      di1=b2[hcol+1];
    df0=b2[HH+hcol];   df1=b2[HH+hcol+1];
    dg0=b2[2*HH+hcol]; dg1=b2[2*HH+hcol+1];
    do0=b2[3*HH+hcol]; do1=b2[3*HH+hcol+1];
  }

  #pragma unroll 1
  for(int t=0;t<TMEL;t++){
    g_wait(gen, ge);   // s_t ready
    const unsigned short* slotin = (t==0) ? ring + (size_t)99*BB*HH
                                          : ring + (size_t)((t-1)%100)*BB*HH;
    stage_h(hs, slotin, bg, tid);
    __syncthreads();
    f32x4 acc = {0.f,0.f,0.f,0.f};
    if(t == 0){
      const unsigned short* wsrc = WhhdS + (size_t)tile*32*64*8;
      #pragma unroll
      for(int kt=0;kt<32;kt++){
        bfv8 wf = *(const bfv8*)(const void*)(wsrc + ((size_t)kt*64 + l)*8);
        bfv8 hv = *(const bfv8*)(const void*)((const char*)hs + ((hbase + kt*64) ^ hswz));
        acc = mfma16(hv, wf, acc);
      }
    } else {
      #pragma unroll
      for(int kt=0;kt<32;kt++){
        bfv8 hv = *(const bfv8*)(const void*)((const char*)hs + ((hbase + kt*64) ^ hswz));
        acc = mfma16(hv, bf[kt], acc);
      }
    }
    {
      int rr = (l>>4)*4;
      #pragma unroll
      for(int q=0;q<4;q++) Gs[rr+q][wvi*16 + fr] = acc[q];
    }
    __syncthreads();
    if(tid < 256){
      float bi0=di0,bi1=di1,bf0=df0,bf1=df1,bg0=dg0,bg1=dg1,bo0=do0,bo1=do1;
      if(t==0){
        bi0=bd[hcol];      bi1=bd[hcol+1];
        bf0=bd[HH+hcol];   bf1=bd[HH+hcol+1];
        bg0=bd[2*HH+hcol]; bg1=bd[2*HH+hcol+1];
        bo0=bd[3*HH+hcol]; bo1=bd[3*HH+hcol+1];
      }
      float gi0 = Gs[lr][lc]    + bi0, gi1 = Gs[lr][lc+1] + bi1;
      float gf0 = Gs[lr][32+lc] + bf0, gf1 = Gs[lr][33+lc] + bf1;
      float gg0 = Gs[lr][64+lc] + bg0, gg1 = Gs[lr][65+lc] + bg1;
      float go0 = Gs[lr][96+lc] + bo0, go1 = Gs[lr][97+lc] + bo1;
      float c20 = sigm(gf0)*cs0 + sigm(gi0)*tanhf(gg0);
      float c21 = sigm(gf1)*cs1 + sigm(gi1)*tanhf(gg1);
      cs0 = c20; cs1 = c21;
      float h20 = sigm(go0)*tanhf(c20);
      float h21 = sigm(go1)*tanhf(c21);
      unsigned int hn = (unsigned)f2b(h20) | ((unsigned)f2b(h21)<<16);
      unsigned short* outslot = ring + (size_t)(t%100)*BB*HH;
      __hip_atomic_store((unsigned int*)(outslot + (size_t)(bg*16+lr)*HH + hcol), hn,
                         __ATOMIC_RELAXED, __HIP_MEMORY_SCOPE_AGENT);
    }
    g_arrive(cnt, gen); ge++;

    if((t%100)==99){
      g_wait(gen, ge);   // all 100 slots final
      int tbase = t - 99;
      #pragma unroll 1
      for(int s = cg; s < 100; s += 32){
        stage_h(hs, ring + (size_t)s*BB*HH, bg, tid);
        __syncthreads();
        int tout = tbase + s;
        #pragma unroll 1
        for(int pass=0; pass<2; pass++){
          int nt = (pass==0) ? wvi : 8;
          if(pass==1 && wvi!=0) break;
          const unsigned short* wsrc = WpgS + (size_t)nt*32*64*8;
          f32x4 acc = {0.f,0.f,0.f,0.f};
          #pragma unroll
          for(int kt=0;kt<32;kt++){
            bfv8 wf = *(const bfv8*)(const void*)(wsrc + ((size_t)kt*64 + l)*8);
            bfv8 hv = *(const bfv8*)(const void*)((const char*)hs + ((hbase + kt*64) ^ hswz));
            acc = mfma16(hv, wf, acc);
          }
          int n = nt*16 + fr;
          #pragma unroll
          for(int q=0;q<4;q++){
            int b = bg*16 + (l>>4)*4 + q;
            bool msk = tout > mlen[b];
            if(n < MELD)
              outmel[((size_t)b*TMEL + tout)*MELD + n] = msk ? 0.f : acc[q]+bp[n];
            else if(n == MELD)
              outgate[(size_t)b*TMEL + tout] = msk ? 1000.f : acc[q]+bgp[0];
          }
        }
        __syncthreads();
      }
      g_arrive(cnt, gen); ge++;
    }
  }
}

__global__ void k_mask(const int* __restrict__ mlen, float* __restrict__ om){
  int idx=blockIdx.x*256+threadIdx.x; if(idx>=BB*TMEL) return;
  int b=idx/TMEL, t=idx%TMEL;
  om[idx] = (t > mlen[b]) ? 1.f : 0.f;
}

extern "C" void kernel_launch(void* const* d_in, const int* in_sizes, int n_in,
                              void* d_out, int out_size, void* d_ws, size_t ws_size,
                              hipStream_t stream){
  (void)in_sizes; (void)n_in; (void)out_size; (void)ws_size;
  const int*   x    = (const int*)d_in[0];
  const int*   tlen = (const int*)d_in[1];
  const int*   mlen = (const int*)d_in[3];
  const float* emb  = (const float*)d_in[4];
  const float* elW  = (const float*)d_in[5];
  const float* elb  = (const float*)d_in[6];
  const float* c1W  = (const float*)d_in[7];
  const float* c1b  = (const float*)d_in[8];
  const float* g1   = (const float*)d_in[9];
  const float* be1  = (const float*)d_in[10];
  const float* c2W  = (const float*)d_in[11];
  const float* c2b  = (const float*)d_in[12];
  const float* g2   = (const float*)d_in[13];
  const float* be2  = (const float*)d_in[14];
  const float* Wihe = (const float*)d_in[15];
  const float* Whhe = (const float*)d_in[16];
  const float* bhe  = (const float*)d_in[17];
  const float* Wihd = (const float*)d_in[18];
  const float* Whhd = (const float*)d_in[19];
  const float* bhd  = (const float*)d_in[20];
  const float* Wp   = (const float*)d_in[21];
  const float* bp   = (const float*)d_in[22];
  const float* Wg   = (const float*)d_in[23];
  const float* bg   = (const float*)d_in[24];

  float* ws = (float*)d_ws;
  float* proj = ws + OFF_PROJ;
  float* T1   = ws + OFF_T1;
  unsigned short* Wr2b = (unsigned short*)(ws + OFF_WR2);
  float* bb1 = ws + OFF_BB1;
  float* bb2 = ws + OFF_BB2;
  float* b2  = ws + OFF_B2;
  float* W2c = ws + OFF_W2C;
  unsigned int* bar = (unsigned int*)(ws + OFF_BAR);
  unsigned short* WencR = (unsigned short*)(ws + OFF_WENCR);
  unsigned short* WihS  = (unsigned short*)(ws + OFF_WIHS);
  unsigned short* W2cR  = (unsigned short*)(ws + OFF_W2CR);
  unsigned short* WhhdS = (unsigned short*)(ws + OFF_WHHDS);
  unsigned short* WpgS  = (unsigned short*)(ws + OFF_WPGS);
  unsigned short* h2b   = (unsigned short*)(ws + OFF_H2B);
  unsigned short* h1pb  = (unsigned short*)(ws + OFF_RING); // conv scratch
  unsigned short* ring  = (unsigned short*)(ws + OFF_RING); // alias after conv2

  float* outmel  = (float*)d_out;
  float* outgate = outmel + (size_t)BB*TMEL*MELD;
  float* outmask = outgate + (size_t)BB*TMEL;

  hipMemsetAsync(bar, 0, 2048, stream);

  k_proj<<<VV,256,0,stream>>>(emb, elW, elb, proj);
  k_t1<<<dim3(VV,3),256,0,stream>>>(proj, c1W, g1, T1);
  k_wr2<<<(EE*3*EE+255)/256,256,0,stream>>>(c2W, g2, Wr2b);
  k_bb<<<2,256,0,stream>>>(c1b,g1,be1,c2b,g2,be2,bb1,bb2);
  k_b2<<<16,256,0,stream>>>(bhd, Wihd, bp, b2);
  k_w2c<<<dim3(4096/8,HH/256),256,0,stream>>>(Whhd, Wihd, Wp, W2c);
  k_pack<<<256,256,0,stream>>>(Whhe, WencR, 32, 1024);
  k_pack<<<256,256,0,stream>>>(Wihe, WihS, 16, 512);
  k_pack<<<256,256,0,stream>>>(W2c,  W2cR, 32, 1024);
  k_pack<<<256,256,0,stream>>>(Whhd, WhhdS, 32, 1024);
  k_pack_pg<<<9,256,0,stream>>>(Wp, Wg, WpgS);
  k_pad<<<256,256,0,stream>>>(h1pb);
  k_conv1<<<65536,256,0,stream>>>(x, T1, bb1, h1pb);
  k_conv2mm<<<dim3(BB,2,32),256,0,stream>>>(h1pb, Wr2b, bb2, h2b);

  void* kargs[] = {
    (void*)&h2b, (void*)&ring, (void*)&WencR, (void*)&WihS, (void*)&W2cR, (void*)&WhhdS,
    (void*)&WpgS, (void*)&bhe, (void*)&bhd, (void*)&b2, (void*)&bp, (void*)&bg,
    (void*)&bar, (void*)&tlen, (void*)&mlen, (void*)&outmel, (void*)&outgate
  };
  hipLaunchCooperativeKernel((void*)k_recur, dim3(256), dim3(512), kargs, 0u, stream);

  k_mask<<<(BB*TMEL+255)/256,256,0,stream>>>(mlen, outmask);
}

// Round 7
// 14057.185 us; speedup vs baseline: 1.2966x; 1.0004x over previous
//
#include <hip/hip_runtime.h>
#include <math.h>

#define BB 128
#define TT 256
#define TMEL 800
#define EE 512
#define HH 1024
#define MELD 128
#define VV 256

// ws offsets (float units)
#define OFF_PROJ  0u
#define OFF_T1    131072u
#define OFF_WR2   524288u
#define OFF_BB1   1310720u
#define OFF_BB2   1311232u
#define OFF_B2    1311744u
#define OFF_W2C   1315840u
#define OFF_BAR   5510144u
#define OFF_WENCR 5522688u
#define OFF_WIHS  7619840u
#define OFF_W2CR  8668416u
#define OFF_WHHDS 10765568u
#define OFF_WPGS  12862720u
#define OFF_H2B   12936448u
#define OFF_RING  21325056u   /* aliases h1pb (dead after conv2) */

typedef __bf16 bfv8 __attribute__((ext_vector_type(8)));
typedef float f32x4 __attribute__((ext_vector_type(4)));

__device__ __forceinline__ unsigned short f2b(float f){
  union { float f; unsigned u; } v; v.f = f;
  unsigned u = v.u;
  return (unsigned short)((u + 0x7fffu + ((u>>16)&1u)) >> 16);
}
__device__ __forceinline__ float sigm(float x){ return 1.0f/(1.0f+expf(-x)); }

__device__ __forceinline__ f32x4 mfma16(bfv8 a, bfv8 b, f32x4 c){
  return __builtin_amdgcn_mfma_f32_16x16x32_bf16(a, b, c, 0, 0, 0);
}

// ---- fp32 precompute kernels ----

__global__ void k_proj(const float* __restrict__ emb, const float* __restrict__ W,
                       const float* __restrict__ bias, float* __restrict__ proj){
  __shared__ float er[EE];
  int v = blockIdx.x;
  for(int i=threadIdx.x;i<EE;i+=256) er[i]=emb[v*EE+i];
  __syncthreads();
  for(int e=threadIdx.x;e<EE;e+=256){
    const float* wr = W + e*EE;
    float acc=0.f;
    for(int k=0;k<EE;k+=4){
      float4 w4 = *(const float4*)(wr+k);
      acc += er[k]*w4.x + er[k+1]*w4.y + er[k+2]*w4.z + er[k+3]*w4.w;
    }
    proj[v*EE+e] = acc + bias[e];
  }
}

__global__ void k_t1(const float* __restrict__ proj, const float* __restrict__ W1,
                     const float* __restrict__ g1, float* __restrict__ T1){
  __shared__ float pr[EE];
  int v = blockIdx.x; int k3 = blockIdx.y;
  for(int i=threadIdx.x;i<EE;i+=256) pr[i]=proj[v*EE+i];
  __syncthreads();
  const float s = rsqrtf(1.f+1e-5f);
  for(int c=threadIdx.x;c<EE;c+=256){
    float acc=0.f;
    const float* w = W1 + c*EE*3 + k3;
    for(int ci=0;ci<EE;ci++) acc += pr[ci]*w[ci*3];
    T1[(v*3+k3)*EE+c] = g1[c]*s*acc;
  }
}

__global__ void k_wr2(const float* __restrict__ W2, const float* __restrict__ g2,
                      unsigned short* __restrict__ Wr){
  int idx = blockIdx.x*256+threadIdx.x;
  if(idx >= EE*3*EE) return;
  int c = idx/1536; int r = idx%1536; int k3 = r/EE; int ci = r%EE;
  const float s = rsqrtf(1.f+1e-5f);
  Wr[idx] = f2b(g2[c]*s*W2[(c*EE+ci)*3+k3]);
}

__global__ void k_bb(const float* __restrict__ b1,const float* __restrict__ g1,const float* __restrict__ be1,
                     const float* __restrict__ b2,const float* __restrict__ g2,const float* __restrict__ be2,
                     float* __restrict__ bb1, float* __restrict__ bb2){
  int c = threadIdx.x + blockIdx.x*256; if(c>=EE) return;
  const float s = rsqrtf(1.f+1e-5f);
  bb1[c] = g1[c]*s*b1[c] + be1[c];
  bb2[c] = g2[c]*s*b2[c] + be2[c];
}

__global__ void k_b2(const float* __restrict__ bd, const float* __restrict__ Wih,
                     const float* __restrict__ bp, float* __restrict__ b2){
  int j = blockIdx.x*256+threadIdx.x; if(j>=4096) return;
  float acc = bd[j];
  const float* w = Wih + j*MELD;
  for(int m=0;m<MELD;m++) acc += w[m]*bp[m];
  b2[j] = acc;
}

__global__ void k_w2c(const float* __restrict__ Whh, const float* __restrict__ Wih,
                      const float* __restrict__ Wp, float* __restrict__ W2c){
  __shared__ float wl[8][MELD];
  int j0 = blockIdx.x*8; int k = blockIdx.y*256 + threadIdx.x;
  for(int i=threadIdx.x;i<8*MELD;i+=256) wl[i/MELD][i%MELD] = Wih[(j0+i/MELD)*MELD + (i%MELD)];
  __syncthreads();
  float acc[8];
  #pragma unroll
  for(int jj=0;jj<8;jj++) acc[jj]=Whh[(j0+jj)*HH+k];
  for(int m=0;m<MELD;m++){
    float wp = Wp[m*HH+k];
    #pragma unroll
    for(int jj=0;jj<8;jj++) acc[jj] += wl[jj][m]*wp;
  }
  #pragma unroll
  for(int jj=0;jj<8;jj++) W2c[(j0+jj)*HH+k] = acc[jj];
}

// ---- fragment packing ----
__global__ void k_pack(const float* __restrict__ src, unsigned short* __restrict__ dst,
                       int NKT, int K){
  int tile = blockIdx.x;
  int cg = tile>>3, wv = tile&7;
  int tot = NKT*64*8;
  for(int i=threadIdx.x; i<tot; i+=256){
    int kt = i>>9; int l = (i>>3)&63; int e = i&7;
    int j = (wv>>1)*1024 + cg*32 + (wv&1)*16 + (l&15);
    int k = ((l>>4)<<3) + kt*32 + e;
    dst[((size_t)(tile*NKT + kt)*64 + l)*8 + e] = f2b(src[(size_t)j*K + k]);
  }
}

__global__ void k_pack_pg(const float* __restrict__ Wp, const float* __restrict__ Wg,
                          unsigned short* __restrict__ dst){
  int nt = blockIdx.x; // 0..8
  for(int i=threadIdx.x; i<32*64*8; i+=256){
    int kt = i>>9; int l = (i>>3)&63; int e = i&7;
    int n = nt*16 + (l&15);
    int k = ((l>>4)<<3) + kt*32 + e;
    float v = (n<MELD)? Wp[(size_t)n*HH+k] : (n==MELD? Wg[k] : 0.f);
    dst[((size_t)(nt*32 + kt)*64 + l)*8 + e] = f2b(v);
  }
}

// ---- conv path ----

__global__ void k_pad(unsigned short* __restrict__ h1pb){
  int idx = blockIdx.x*256+threadIdx.x;
  int c = idx & 511; int b = idx >> 9;
  h1pb[((size_t)b*258)*EE + c] = 0;
  h1pb[((size_t)b*258 + 257)*EE + c] = 0;
}

__global__ void k_conv1(const int* __restrict__ x, const float* __restrict__ T1,
                        const float* __restrict__ bb1, unsigned short* __restrict__ h1pb){
  int idx = blockIdx.x*256+threadIdx.x;
  int c = idx & 511; int bt = idx >> 9; int t = bt & 255; int b = bt >> 8;
  float acc = bb1[c];
  if(t > 0)    acc += T1[(size_t)(x[b*TT+t-1]*3+0)*EE+c];
               acc += T1[(size_t)(x[b*TT+t  ]*3+1)*EE+c];
  if(t < TT-1) acc += T1[(size_t)(x[b*TT+t+1]*3+2)*EE+c];
  h1pb[((size_t)b*258 + t + 1)*EE + c] = f2b(fmaxf(acc, 0.f));
}

template<int NKT>
__device__ __forceinline__ void mm_seg_stream(const unsigned short* A, int lda,
    const unsigned short* Wrow, f32x4& acc0, f32x4& acc1, int l, int wv){
  int r0 = wv*32 + (l&15);
  int k8 = (l>>4)*8;
  const unsigned short* a0 = A + (size_t)r0*lda + k8;
  const unsigned short* a1 = a0 + 16*lda;
  const unsigned short* wp = Wrow + k8;
  #pragma unroll
  for(int kt=0;kt<NKT;kt++){
    bfv8 bv = *(const bfv8*)(const void*)(wp + kt*32);
    acc0 = mfma16(*(const bfv8*)(const void*)(a0 + kt*32), bv, acc0);
    acc1 = mfma16(*(const bfv8*)(const void*)(a1 + kt*32), bv, acc1);
  }
}

__global__ __launch_bounds__(256,2) void k_conv2mm(const unsigned short* __restrict__ h1pb,
    const unsigned short* __restrict__ Wr2b, const float* __restrict__ bb2,
    unsigned short* __restrict__ h2b){
  int b = blockIdx.x;    // 0..127
  int th = blockIdx.y;   // 0..1
  int nt = blockIdx.z;   // 0..31
  int tid=threadIdx.x; int wv=tid>>6, l=tid&63;
  const unsigned short* A = h1pb + ((size_t)b*258 + th*128)*EE;
  const unsigned short* Wrow = Wr2b + (size_t)(nt*16+(l&15))*1536;
  f32x4 acc0={0,0,0,0}, acc1={0,0,0,0};
  mm_seg_stream<48>(A, EE, Wrow, acc0, acc1, l, wv);
  int rr=(l>>4)*4, cc=l&15;
  int n = nt*16+cc;
  float bias = bb2[n];
  #pragma unroll
  for(int mi=0;mi<2;mi++){
    f32x4 acc = mi?acc1:acc0;
    int tb = th*128 + wv*32 + mi*16 + rr;
    #pragma unroll
    for(int q=0;q<4;q++){
      float v = fmaxf(acc[q]+bias, 0.f);
      h2b[((size_t)(tb+q)*BB + b)*EE + n] = f2b(v);
    }
  }
}

// ---- group barrier: all relaxed (no buffer_inv/wbl2). __syncthreads drains
// vmcnt per wave before the arrive, so agent-scope UC h-stores are acked at
// the coherence point before gen increments; consumers re-load via UC. ----
__device__ __forceinline__ void g_arrive(unsigned int* cnt, unsigned int* gen){
  __syncthreads();
  if(threadIdx.x == 0){
    unsigned int old = __hip_atomic_fetch_add(cnt, 1u, __ATOMIC_RELAXED, __HIP_MEMORY_SCOPE_AGENT);
    if(old == 31u){
      __hip_atomic_store(cnt, 0u, __ATOMIC_RELAXED, __HIP_MEMORY_SCOPE_AGENT);
      __hip_atomic_fetch_add(gen, 1u, __ATOMIC_RELAXED, __HIP_MEMORY_SCOPE_AGENT);
    }
  }
}
__device__ __forceinline__ void g_wait(unsigned int* gen, unsigned int target){
  if(threadIdx.x == 0){
    while(__hip_atomic_load(gen, __ATOMIC_RELAXED, __HIP_MEMORY_SCOPE_AGENT) < target)
      __builtin_amdgcn_s_sleep(1);
  }
  asm volatile("" ::: "memory");
  __syncthreads();
}

// stage 16 rows x 1024 cols of a ring slot into swizzled LDS
__device__ __forceinline__ void stage_h(unsigned short* hs, const unsigned short* slotp,
                                        int bg, int tid){
  for(int i = tid; i < 4096; i += 512){
    int r = i >> 8, c8 = i & 255;
    const unsigned long long* p =
      (const unsigned long long*)(slotp + (size_t)(bg*16+r)*HH + c8*4);
    unsigned long long v = __hip_atomic_load(p, __ATOMIC_RELAXED, __HIP_MEMORY_SCOPE_AGENT);
    *(unsigned long long*)((char*)hs + ((r*2048 + c8*8) ^ ((r&7)<<4))) = v;
  }
}

// ---- persistent recurrence: 256 WGs = 8 batch-groups x 32 col-groups.
// __launch_bounds__(512,1): 256-VGPR budget so bf[32] (128 VGPR) is GENUINELY
// register-resident -- at (512,2) the 128-VGPR cap forced the compiler to
// re-stream 64 MB/step of weights from L3 (round 4/6 FETCH evidence). ----
__global__ __launch_bounds__(512,1) void k_recur(
  const unsigned short* __restrict__ h2b, unsigned short* __restrict__ ring,
  const unsigned short* __restrict__ WencR, const unsigned short* __restrict__ WihS,
  const unsigned short* __restrict__ W2cR, const unsigned short* __restrict__ WhhdS,
  const unsigned short* __restrict__ WpgS,
  const float* __restrict__ bhe, const float* __restrict__ bd, const float* __restrict__ b2,
  const float* __restrict__ bp, const float* __restrict__ bgp,
  unsigned int* __restrict__ bar,
  const int* __restrict__ tlen, const int* __restrict__ mlen,
  float* __restrict__ outmel, float* __restrict__ outgate)
{
  __shared__ __align__(16) unsigned short hs[16*1024];  // 32KB
  __shared__ __align__(16) unsigned short Xs[16*512];   // 16KB
  __shared__ float Gs[16][132];

  const int bid = blockIdx.x;
  const int bg = bid >> 5, cg = bid & 31;
  const int tid = threadIdx.x;
  const int wvi = tid >> 6, l = tid & 63;
  const int tile = cg*8 + wvi;
  unsigned int* cnt = bar + bg*32;
  unsigned int* gen = bar + 256 + bg*32;
  unsigned int ge = 1;

  const int fr = l & 15;
  const int hswz = (fr & 7) << 4;
  const int hbase = fr*2048 + ((l>>4)<<4);
  const int xbase = fr*1024 + ((l>>4)<<4);

  const int lr = tid >> 4;
  const int lc = (tid & 15) * 2;
  const int hcol = cg*32 + lc;
  float cs0 = 0.f, cs1 = 0.f;
  unsigned int hp = 0u;
  int mylen = 0;
  if(tid < 256) mylen = tlen[bg*16 + lr];

  // zero enc h_0 (slot 100)
  if(tid < 128){
    int r = tid >> 3, c4 = (tid & 7) * 4;
    unsigned long long* p = (unsigned long long*)
      (ring + (size_t)100*BB*HH + (size_t)(bg*16+r)*HH + cg*32 + c4);
    __hip_atomic_store(p, 0ull, __ATOMIC_RELAXED, __HIP_MEMORY_SCOPE_AGENT);
  }
  g_arrive(cnt, gen);

  bfv8 bf[32];

  // ================= encoder: 256 steps =================
  #pragma unroll 1
  for(int kt=0;kt<32;kt++)
    bf[kt] = *(const bfv8*)(const void*)(WencR + ((size_t)(tile*32+kt)*64 + l)*8);

  float ei0=0,ei1=0,ef0=0,ef1=0,eg0=0,eg1=0,eo0=0,eo1=0;
  if(tid < 256){
    ei0=bhe[hcol];      ei1=bhe[hcol+1];
    ef0=bhe[HH+hcol];   ef1=bhe[HH+hcol+1];
    eg0=bhe[2*HH+hcol]; eg1=bhe[2*HH+hcol+1];
    eo0=bhe[3*HH+hcol]; eo1=bhe[3*HH+hcol+1];
  }

  #pragma unroll 1
  for(int t=0;t<TT;t++){
    {
      const uint4* src = (const uint4*)(h2b + (size_t)(t*BB + bg*16)*EE);
      for(int i = tid; i < 1024; i += 512){
        int r = i >> 6, c16 = i & 63;
        uint4 v = src[r*64 + c16];
        *(uint4*)((char*)Xs + ((r*1024 + c16*16) ^ ((r&7)<<4))) = v;
      }
    }
    __syncthreads();
    f32x4 acc = {0.f,0.f,0.f,0.f};
    {
      const unsigned short* wsrc = WihS + (size_t)tile*16*64*8;
      #pragma unroll
      for(int kt=0;kt<16;kt++){
        bfv8 wf = *(const bfv8*)(const void*)(wsrc + ((size_t)kt*64 + l)*8);
        bfv8 xv = *(const bfv8*)(const void*)((const char*)Xs + ((xbase + kt*64) ^ hswz));
        acc = mfma16(xv, wf, acc);
      }
    }
    g_wait(gen, ge);   // h_t ready
    stage_h(hs, ring + (size_t)(100 + (t&1))*BB*HH, bg, tid);
    __syncthreads();
    #pragma unroll
    for(int kt=0;kt<32;kt++){
      bfv8 hv = *(const bfv8*)(const void*)((const char*)hs + ((hbase + kt*64) ^ hswz));
      acc = mfma16(hv, bf[kt], acc);
    }
    {
      int rr = (l>>4)*4;
      #pragma unroll
      for(int q=0;q<4;q++) Gs[rr+q][wvi*16 + fr] = acc[q];
    }
    __syncthreads();
    if(tid < 256){
      float gi0 = Gs[lr][lc]    + ei0, gi1 = Gs[lr][lc+1] + ei1;
      float gf0 = Gs[lr][32+lc] + ef0, gf1 = Gs[lr][33+lc] + ef1;
      float gg0 = Gs[lr][64+lc] + eg0, gg1 = Gs[lr][65+lc] + eg1;
      float go0 = Gs[lr][96+lc] + eo0, go1 = Gs[lr][97+lc] + eo1;
      float c20 = sigm(gf0)*cs0 + sigm(gi0)*tanhf(gg0);
      float c21 = sigm(gf1)*cs1 + sigm(gi1)*tanhf(gg1);
      float h20 = sigm(go0)*tanhf(c20);
      float h21 = sigm(go1)*tanhf(c21);
      if(t < mylen){
        cs0 = c20; cs1 = c21;
        hp = (unsigned)f2b(h20) | ((unsigned)f2b(h21)<<16);
      }
      unsigned short* outslot = (t==TT-1) ? (ring + (size_t)99*BB*HH)
                                          : (ring + (size_t)(100 + ((t+1)&1))*BB*HH);
      __hip_atomic_store((unsigned int*)(outslot + (size_t)(bg*16+lr)*HH + hcol), hp,
                         __ATOMIC_RELAXED, __HIP_MEMORY_SCOPE_AGENT);
    }
    g_arrive(cnt, gen); ge++;
  }

  // ================= decoder: 800 steps =================
  #pragma unroll 1
  for(int kt=0;kt<32;kt++)
    bf[kt] = *(const bfv8*)(const void*)(W2cR + ((size_t)(tile*32+kt)*64 + l)*8);

  float di0=0,di1=0,df0=0,df1=0,dg0=0,dg1=0,do0=0,do1=0;
  if(tid < 256){
    di0=b2[hcol];      di1=b2[hcol+1];
    df0=b2[HH+hcol];   df1=b2[HH+hcol+1];
    dg0=b2[2*HH+hcol]; dg1=b2[2*HH+hcol+1];
    do0=b2[3*HH+hcol]; do1=b2[3*HH+hcol+1];
  }

  #pragma unroll 1
  for(int t=0;t<TMEL;t++){
    g_wait(gen, ge);   // s_t ready
    const unsigned short* slotin = (t==0) ? ring + (size_t)99*BB*HH
                                          : ring + (size_t)((t-1)%100)*BB*HH;
    stage_h(hs, slotin, bg, tid);
    __syncthreads();
    f32x4 acc = {0.f,0.f,0.f,0.f};
    if(t == 0){
      const unsigned short* wsrc = WhhdS + (size_t)tile*32*64*8;
      #pragma unroll
      for(int kt=0;kt<32;kt++){
        bfv8 wf = *(const bfv8*)(const void*)(wsrc + ((size_t)kt*64 + l)*8);
        bfv8 hv = *(const bfv8*)(const void*)((const char*)hs + ((hbase + kt*64) ^ hswz));
        acc = mfma16(hv, wf, acc);
      }
    } else {
      #pragma unroll
      for(int kt=0;kt<32;kt++){
        bfv8 hv = *(const bfv8*)(const void*)((const char*)hs + ((hbase + kt*64) ^ hswz));
        acc = mfma16(hv, bf[kt], acc);
      }
    }
    {
      int rr = (l>>4)*4;
      #pragma unroll
      for(int q=0;q<4;q++) Gs[rr+q][wvi*16 + fr] = acc[q];
    }
    __syncthreads();
    if(tid < 256){
      float bi0=di0,bi1=di1,bf0=df0,bf1=df1,bg0=dg0,bg1=dg1,bo0=do0,bo1=do1;
      if(t==0){
        bi0=bd[hcol];      bi1=bd[hcol+1];
        bf0=bd[HH+hcol];   bf1=bd[HH+hcol+1];
        bg0=bd[2*HH+hcol]; bg1=bd[2*HH+hcol+1];
        bo0=bd[3*HH+hcol]; bo1=bd[3*HH+hcol+1];
      }
      float gi0 = Gs[lr][lc]    + bi0, gi1 = Gs[lr][lc+1] + bi1;
      float gf0 = Gs[lr][32+lc] + bf0, gf1 = Gs[lr][33+lc] + bf1;
      float gg0 = Gs[lr][64+lc] + bg0, gg1 = Gs[lr][65+lc] + bg1;
      float go0 = Gs[lr][96+lc] + bo0, go1 = Gs[lr][97+lc] + bo1;
      float c20 = sigm(gf0)*cs0 + sigm(gi0)*tanhf(gg0);
      float c21 = sigm(gf1)*cs1 + sigm(gi1)*tanhf(gg1);
      cs0 = c20; cs1 = c21;
      float h20 = sigm(go0)*tanhf(c20);
      float h21 = sigm(go1)*tanhf(c21);
      unsigned int hn = (unsigned)f2b(h20) | ((unsigned)f2b(h21)<<16);
      unsigned short* outslot = ring + (size_t)(t%100)*BB*HH;
      __hip_atomic_store((unsigned int*)(outslot + (size_t)(bg*16+lr)*HH + hcol), hn,
                         __ATOMIC_RELAXED, __HIP_MEMORY_SCOPE_AGENT);
    }
    g_arrive(cnt, gen); ge++;

    if((t%100)==99){
      g_wait(gen, ge);   // all 100 slots final
      int tbase = t - 99;
      #pragma unroll 1
      for(int s = cg; s < 100; s += 32){
        stage_h(hs, ring + (size_t)s*BB*HH, bg, tid);
        __syncthreads();
        int tout = tbase + s;
        #pragma unroll 1
        for(int pass=0; pass<2; pass++){
          int nt = (pass==0) ? wvi : 8;
          if(pass==1 && wvi!=0) break;
          const unsigned short* wsrc = WpgS + (size_t)nt*32*64*8;
          f32x4 acc = {0.f,0.f,0.f,0.f};
          #pragma unroll
          for(int kt=0;kt<32;kt++){
            bfv8 wf = *(const bfv8*)(const void*)(wsrc + ((size_t)kt*64 + l)*8);
            bfv8 hv = *(const bfv8*)(const void*)((const char*)hs + ((hbase + kt*64) ^ hswz));
            acc = mfma16(hv, wf, acc);
          }
          int n = nt*16 + fr;
          #pragma unroll
          for(int q=0;q<4;q++){
            int b = bg*16 + (l>>4)*4 + q;
            bool msk = tout > mlen[b];
            if(n < MELD)
              outmel[((size_t)b*TMEL + tout)*MELD + n] = msk ? 0.f : acc[q]+bp[n];
            else if(n == MELD)
              outgate[(size_t)b*TMEL + tout] = msk ? 1000.f : acc[q]+bgp[0];
          }
        }
        __syncthreads();
      }
      g_arrive(cnt, gen); ge++;
    }
  }
}

__global__ void k_mask(const int* __restrict__ mlen, float* __restrict__ om){
  int idx=blockIdx.x*256+threadIdx.x; if(idx>=BB*TMEL) return;
  int b=idx/TMEL, t=idx%TMEL;
  om[idx] = (t > mlen[b]) ? 1.f : 0.f;
}

extern "C" void kernel_launch(void* const* d_in, const int* in_sizes, int n_in,
                              void* d_out, int out_size, void* d_ws, size_t ws_size,
                              hipStream_t stream){
  (void)in_sizes; (void)n_in; (void)out_size; (void)ws_size;
  const int*   x    = (const int*)d_in[0];
  const int*   tlen = (const int*)d_in[1];
  const int*   mlen = (const int*)d_in[3];
  const float* emb  = (const float*)d_in[4];
  const float* elW  = (const float*)d_in[5];
  const float* elb  = (const float*)d_in[6];
  const float* c1W  = (const float*)d_in[7];
  const float* c1b  = (const float*)d_in[8];
  const float* g1   = (const float*)d_in[9];
  const float* be1  = (const float*)d_in[10];
  const float* c2W  = (const float*)d_in[11];
  const float* c2b  = (const float*)d_in[12];
  const float* g2   = (const float*)d_in[13];
  const float* be2  = (const float*)d_in[14];
  const float* Wihe = (const float*)d_in[15];
  const float* Whhe = (const float*)d_in[16];
  const float* bhe  = (const float*)d_in[17];
  const float* Wihd = (const float*)d_in[18];
  const float* Whhd = (const float*)d_in[19];
  const float* bhd  = (const float*)d_in[20];
  const float* Wp   = (const float*)d_in[21];
  const float* bp   = (const float*)d_in[22];
  const float* Wg   = (const float*)d_in[23];
  const float* bg   = (const float*)d_in[24];

  float* ws = (float*)d_ws;
  float* proj = ws + OFF_PROJ;
  float* T1   = ws + OFF_T1;
  unsigned short* Wr2b = (unsigned short*)(ws + OFF_WR2);
  float* bb1 = ws + OFF_BB1;
  float* bb2 = ws + OFF_BB2;
  float* b2  = ws + OFF_B2;
  float* W2c = ws + OFF_W2C;
  unsigned int* bar = (unsigned int*)(ws + OFF_BAR);
  unsigned short* WencR = (unsigned short*)(ws + OFF_WENCR);
  unsigned short* WihS  = (unsigned short*)(ws + OFF_WIHS);
  unsigned short* W2cR  = (unsigned short*)(ws + OFF_W2CR);
  unsigned short* WhhdS = (unsigned short*)(ws + OFF_WHHDS);
  unsigned short* WpgS  = (unsigned short*)(ws + OFF_WPGS);
  unsigned short* h2b   = (unsigned short*)(ws + OFF_H2B);
  unsigned short* h1pb  = (unsigned short*)(ws + OFF_RING); // conv scratch
  unsigned short* ring  = (unsigned short*)(ws + OFF_RING); // alias after conv2

  float* outmel  = (float*)d_out;
  float* outgate = outmel + (size_t)BB*TMEL*MELD;
  float* outmask = outgate + (size_t)BB*TMEL;

  hipMemsetAsync(bar, 0, 2048, stream);

  k_proj<<<VV,256,0,stream>>>(emb, elW, elb, proj);
  k_t1<<<dim3(VV,3),256,0,stream>>>(proj, c1W, g1, T1);
  k_wr2<<<(EE*3*EE+255)/256,256,0,stream>>>(c2W, g2, Wr2b);
  k_bb<<<2,256,0,stream>>>(c1b,g1,be1,c2b,g2,be2,bb1,bb2);
  k_b2<<<16,256,0,stream>>>(bhd, Wihd, bp, b2);
  k_w2c<<<dim3(4096/8,HH/256),256,0,stream>>>(Whhd, Wihd, Wp, W2c);
  k_pack<<<256,256,0,stream>>>(Whhe, WencR, 32, 1024);
  k_pack<<<256,256,0,stream>>>(Wihe, WihS, 16, 512);
  k_pack<<<256,256,0,stream>>>(W2c,  W2cR, 32, 1024);
  k_pack<<<256,256,0,stream>>>(Whhd, WhhdS, 32, 1024);
  k_pack_pg<<<9,256,0,stream>>>(Wp, Wg, WpgS);
  k_pad<<<256,256,0,stream>>>(h1pb);
  k_conv1<<<65536,256,0,stream>>>(x, T1, bb1, h1pb);
  k_conv2mm<<<dim3(BB,2,32),256,0,stream>>>(h1pb, Wr2b, bb2, h2b);

  void* kargs[] = {
    (void*)&h2b, (void*)&ring, (void*)&WencR, (void*)&WihS, (void*)&W2cR, (void*)&WhhdS,
    (void*)&WpgS, (void*)&bhe, (void*)&bhd, (void*)&b2, (void*)&bp, (void*)&bg,
    (void*)&bar, (void*)&tlen, (void*)&mlen, (void*)&outmel, (void*)&outgate
  };
  hipLaunchCooperativeKernel((void*)k_recur, dim3(256), dim3(512), kargs, 0u, stream);

  k_mask<<<(BB*TMEL+255)/256,256,0,stream>>>(mlen, outmask);
}

// Round 8
// 9224.818 us; speedup vs baseline: 1.9758x; 1.5238x over previous
//
#include <hip/hip_runtime.h>
#include <math.h>

#define BB 128
#define TT 256
#define TMEL 800
#define EE 512
#define HH 1024
#define MELD 128
#define VV 256

// ws offsets (float units)
#define OFF_PROJ  0u
#define OFF_T1    131072u
#define OFF_WR2   524288u
#define OFF_BB1   1310720u
#define OFF_BB2   1311232u
#define OFF_B2    1311744u
#define OFF_W2C   1315840u
#define OFF_BAR   5510144u
#define OFF_WENCR 5522688u
#define OFF_WIHS  7619840u
#define OFF_W2CR  8668416u
#define OFF_WHHDS 10765568u
#define OFF_WPGS  12862720u
#define OFF_H2B   12936448u
#define OFF_RING  21325056u   /* aliases h1pb (dead after conv2) */

typedef __bf16 bfv8 __attribute__((ext_vector_type(8)));
typedef float f32x4 __attribute__((ext_vector_type(4)));

__device__ __forceinline__ unsigned short f2b(float f){
  union { float f; unsigned u; } v; v.f = f;
  unsigned u = v.u;
  return (unsigned short)((u + 0x7fffu + ((u>>16)&1u)) >> 16);
}
__device__ __forceinline__ float sigm(float x){ return 1.0f/(1.0f+expf(-x)); }

__device__ __forceinline__ f32x4 mfma16(bfv8 a, bfv8 b, f32x4 c){
  return __builtin_amdgcn_mfma_f32_16x16x32_bf16(a, b, c, 0, 0, 0);
}

// ---- fp32 precompute kernels ----

__global__ void k_proj(const float* __restrict__ emb, const float* __restrict__ W,
                       const float* __restrict__ bias, float* __restrict__ proj){
  __shared__ float er[EE];
  int v = blockIdx.x;
  for(int i=threadIdx.x;i<EE;i+=256) er[i]=emb[v*EE+i];
  __syncthreads();
  for(int e=threadIdx.x;e<EE;e+=256){
    const float* wr = W + e*EE;
    float acc=0.f;
    for(int k=0;k<EE;k+=4){
      float4 w4 = *(const float4*)(wr+k);
      acc += er[k]*w4.x + er[k+1]*w4.y + er[k+2]*w4.z + er[k+3]*w4.w;
    }
    proj[v*EE+e] = acc + bias[e];
  }
}

__global__ void k_t1(const float* __restrict__ proj, const float* __restrict__ W1,
                     const float* __restrict__ g1, float* __restrict__ T1){
  __shared__ float pr[EE];
  int v = blockIdx.x; int k3 = blockIdx.y;
  for(int i=threadIdx.x;i<EE;i+=256) pr[i]=proj[v*EE+i];
  __syncthreads();
  const float s = rsqrtf(1.f+1e-5f);
  for(int c=threadIdx.x;c<EE;c+=256){
    float acc=0.f;
    const float* w = W1 + c*EE*3 + k3;
    for(int ci=0;ci<EE;ci++) acc += pr[ci]*w[ci*3];
    T1[(v*3+k3)*EE+c] = g1[c]*s*acc;
  }
}

__global__ void k_wr2(const float* __restrict__ W2, const float* __restrict__ g2,
                      unsigned short* __restrict__ Wr){
  int idx = blockIdx.x*256+threadIdx.x;
  if(idx >= EE*3*EE) return;
  int c = idx/1536; int r = idx%1536; int k3 = r/EE; int ci = r%EE;
  const float s = rsqrtf(1.f+1e-5f);
  Wr[idx] = f2b(g2[c]*s*W2[(c*EE+ci)*3+k3]);
}

__global__ void k_bb(const float* __restrict__ b1,const float* __restrict__ g1,const float* __restrict__ be1,
                     const float* __restrict__ b2,const float* __restrict__ g2,const float* __restrict__ be2,
                     float* __restrict__ bb1, float* __restrict__ bb2){
  int c = threadIdx.x + blockIdx.x*256; if(c>=EE) return;
  const float s = rsqrtf(1.f+1e-5f);
  bb1[c] = g1[c]*s*b1[c] + be1[c];
  bb2[c] = g2[c]*s*b2[c] + be2[c];
}

__global__ void k_b2(const float* __restrict__ bd, const float* __restrict__ Wih,
                     const float* __restrict__ bp, float* __restrict__ b2){
  int j = blockIdx.x*256+threadIdx.x; if(j>=4096) return;
  float acc = bd[j];
  const float* w = Wih + j*MELD;
  for(int m=0;m<MELD;m++) acc += w[m]*bp[m];
  b2[j] = acc;
}

__global__ void k_w2c(const float* __restrict__ Whh, const float* __restrict__ Wih,
                      const float* __restrict__ Wp, float* __restrict__ W2c){
  __shared__ float wl[8][MELD];
  int j0 = blockIdx.x*8; int k = blockIdx.y*256 + threadIdx.x;
  for(int i=threadIdx.x;i<8*MELD;i+=256) wl[i/MELD][i%MELD] = Wih[(j0+i/MELD)*MELD + (i%MELD)];
  __syncthreads();
  float acc[8];
  #pragma unroll
  for(int jj=0;jj<8;jj++) acc[jj]=Whh[(j0+jj)*HH+k];
  for(int m=0;m<MELD;m++){
    float wp = Wp[m*HH+k];
    #pragma unroll
    for(int jj=0;jj<8;jj++) acc[jj] += wl[jj][m]*wp;
  }
  #pragma unroll
  for(int jj=0;jj<8;jj++) W2c[(j0+jj)*HH+k] = acc[jj];
}

// ---- fragment packing ----
__global__ void k_pack(const float* __restrict__ src, unsigned short* __restrict__ dst,
                       int NKT, int K){
  int tile = blockIdx.x;
  int cg = tile>>3, wv = tile&7;
  int tot = NKT*64*8;
  for(int i=threadIdx.x; i<tot; i+=256){
    int kt = i>>9; int l = (i>>3)&63; int e = i&7;
    int j = (wv>>1)*1024 + cg*32 + (wv&1)*16 + (l&15);
    int k = ((l>>4)<<3) + kt*32 + e;
    dst[((size_t)(tile*NKT + kt)*64 + l)*8 + e] = f2b(src[(size_t)j*K + k]);
  }
}

__global__ void k_pack_pg(const float* __restrict__ Wp, const float* __restrict__ Wg,
                          unsigned short* __restrict__ dst){
  int nt = blockIdx.x; // 0..8
  for(int i=threadIdx.x; i<32*64*8; i+=256){
    int kt = i>>9; int l = (i>>3)&63; int e = i&7;
    int n = nt*16 + (l&15);
    int k = ((l>>4)<<3) + kt*32 + e;
    float v = (n<MELD)? Wp[(size_t)n*HH+k] : (n==MELD? Wg[k] : 0.f);
    dst[((size_t)(nt*32 + kt)*64 + l)*8 + e] = f2b(v);
  }
}

// ---- conv path ----

__global__ void k_pad(unsigned short* __restrict__ h1pb){
  int idx = blockIdx.x*256+threadIdx.x;
  int c = idx & 511; int b = idx >> 9;
  h1pb[((size_t)b*258)*EE + c] = 0;
  h1pb[((size_t)b*258 + 257)*EE + c] = 0;
}

__global__ void k_conv1(const int* __restrict__ x, const float* __restrict__ T1,
                        const float* __restrict__ bb1, unsigned short* __restrict__ h1pb){
  int idx = blockIdx.x*256+threadIdx.x;
  int c = idx & 511; int bt = idx >> 9; int t = bt & 255; int b = bt >> 8;
  float acc = bb1[c];
  if(t > 0)    acc += T1[(size_t)(x[b*TT+t-1]*3+0)*EE+c];
               acc += T1[(size_t)(x[b*TT+t  ]*3+1)*EE+c];
  if(t < TT-1) acc += T1[(size_t)(x[b*TT+t+1]*3+2)*EE+c];
  h1pb[((size_t)b*258 + t + 1)*EE + c] = f2b(fmaxf(acc, 0.f));
}

template<int NKT>
__device__ __forceinline__ void mm_seg_stream(const unsigned short* A, int lda,
    const unsigned short* Wrow, f32x4& acc0, f32x4& acc1, int l, int wv){
  int r0 = wv*32 + (l&15);
  int k8 = (l>>4)*8;
  const unsigned short* a0 = A + (size_t)r0*lda + k8;
  const unsigned short* a1 = a0 + 16*lda;
  const unsigned short* wp = Wrow + k8;
  #pragma unroll
  for(int kt=0;kt<NKT;kt++){
    bfv8 bv = *(const bfv8*)(const void*)(wp + kt*32);
    acc0 = mfma16(*(const bfv8*)(const void*)(a0 + kt*32), bv, acc0);
    acc1 = mfma16(*(const bfv8*)(const void*)(a1 + kt*32), bv, acc1);
  }
}

__global__ __launch_bounds__(256,2) void k_conv2mm(const unsigned short* __restrict__ h1pb,
    const unsigned short* __restrict__ Wr2b, const float* __restrict__ bb2,
    unsigned short* __restrict__ h2b){
  int b = blockIdx.x;    // 0..127
  int th = blockIdx.y;   // 0..1
  int nt = blockIdx.z;   // 0..31
  int tid=threadIdx.x; int wv=tid>>6, l=tid&63;
  const unsigned short* A = h1pb + ((size_t)b*258 + th*128)*EE;
  const unsigned short* Wrow = Wr2b + (size_t)(nt*16+(l&15))*1536;
  f32x4 acc0={0,0,0,0}, acc1={0,0,0,0};
  mm_seg_stream<48>(A, EE, Wrow, acc0, acc1, l, wv);
  int rr=(l>>4)*4, cc=l&15;
  int n = nt*16+cc;
  float bias = bb2[n];
  #pragma unroll
  for(int mi=0;mi<2;mi++){
    f32x4 acc = mi?acc1:acc0;
    int tb = th*128 + wv*32 + mi*16 + rr;
    #pragma unroll
    for(int q=0;q<4;q++){
      float v = fmaxf(acc[q]+bias, 0.f);
      h2b[((size_t)(tb+q)*BB + b)*EE + n] = f2b(v);
    }
  }
}

// ---- group barrier: all relaxed (no buffer_inv/wbl2). __syncthreads drains
// vmcnt per wave before the arrive, so agent-scope UC h-stores are acked at
// the coherence point before gen increments; consumers re-load via UC. ----
__device__ __forceinline__ void g_arrive(unsigned int* cnt, unsigned int* gen){
  __syncthreads();
  if(threadIdx.x == 0){
    unsigned int old = __hip_atomic_fetch_add(cnt, 1u, __ATOMIC_RELAXED, __HIP_MEMORY_SCOPE_AGENT);
    if(old == 31u){
      __hip_atomic_store(cnt, 0u, __ATOMIC_RELAXED, __HIP_MEMORY_SCOPE_AGENT);
      __hip_atomic_fetch_add(gen, 1u, __ATOMIC_RELAXED, __HIP_MEMORY_SCOPE_AGENT);
    }
  }
}
__device__ __forceinline__ void g_wait(unsigned int* gen, unsigned int target){
  if(threadIdx.x == 0){
    while(__hip_atomic_load(gen, __ATOMIC_RELAXED, __HIP_MEMORY_SCOPE_AGENT) < target)
      __builtin_amdgcn_s_sleep(1);
  }
  asm volatile("" ::: "memory");
  __syncthreads();
}

// stage 16 rows x 1024 cols of a ring slot into swizzled LDS
__device__ __forceinline__ void stage_h(unsigned short* hs, const unsigned short* slotp,
                                        int bg, int tid){
  for(int i = tid; i < 4096; i += 512){
    int r = i >> 8, c8 = i & 255;
    const unsigned long long* p =
      (const unsigned long long*)(slotp + (size_t)(bg*16+r)*HH + c8*4);
    unsigned long long v = __hip_atomic_load(p, __ATOMIC_RELAXED, __HIP_MEMORY_SCOPE_AGENT);
    *(unsigned long long*)((char*)hs + ((r*2048 + c8*8) ^ ((r&7)<<4))) = v;
  }
}

// ---- persistent recurrence: 256 WGs = 8 batch-groups x 32 col-groups.
// Weight fragments live in f32x4 bw[32] with FULLY-UNROLLED statically-indexed
// loads + asm keep-alive: rule-#20 fix. Rounds 4-7 had `#pragma unroll 1` on
// the load loop -> runtime-indexed array def -> compiler rematerialized the
// global loads inside the step loop (VGPR=120, 64 MB/step weight re-stream,
// 35 GB FETCH). Static indices + opaque asm def make the fragments genuinely
// register-resident. ----
__global__ __launch_bounds__(512,1) void k_recur(
  const unsigned short* __restrict__ h2b, unsigned short* __restrict__ ring,
  const unsigned short* __restrict__ WencR, const unsigned short* __restrict__ WihS,
  const unsigned short* __restrict__ W2cR, const unsigned short* __restrict__ WhhdS,
  const unsigned short* __restrict__ WpgS,
  const float* __restrict__ bhe, const float* __restrict__ bd, const float* __restrict__ b2,
  const float* __restrict__ bp, const float* __restrict__ bgp,
  unsigned int* __restrict__ bar,
  const int* __restrict__ tlen, const int* __restrict__ mlen,
  float* __restrict__ outmel, float* __restrict__ outgate)
{
  __shared__ __align__(16) unsigned short hs[16*1024];  // 32KB
  __shared__ __align__(16) unsigned short Xs[16*512];   // 16KB
  __shared__ float Gs[16][132];

  const int bid = blockIdx.x;
  const int bg = bid >> 5, cg = bid & 31;
  const int tid = threadIdx.x;
  const int wvi = tid >> 6, l = tid & 63;
  const int tile = cg*8 + wvi;
  unsigned int* cnt = bar + bg*32;
  unsigned int* gen = bar + 256 + bg*32;
  unsigned int ge = 1;

  const int fr = l & 15;
  const int hswz = (fr & 7) << 4;
  const int hbase = fr*2048 + ((l>>4)<<4);
  const int xbase = fr*1024 + ((l>>4)<<4);

  const int lr = tid >> 4;
  const int lc = (tid & 15) * 2;
  const int hcol = cg*32 + lc;
  float cs0 = 0.f, cs1 = 0.f;
  unsigned int hp = 0u;
  int mylen = 0;
  if(tid < 256) mylen = tlen[bg*16 + lr];

  // zero enc h_0 (slot 100)
  if(tid < 128){
    int r = tid >> 3, c4 = (tid & 7) * 4;
    unsigned long long* p = (unsigned long long*)
      (ring + (size_t)100*BB*HH + (size_t)(bg*16+r)*HH + cg*32 + c4);
    __hip_atomic_store(p, 0ull, __ATOMIC_RELAXED, __HIP_MEMORY_SCOPE_AGENT);
  }
  g_arrive(cnt, gen);

  f32x4 bw[32];

  // ================= encoder: 256 steps =================
  {
    const f32x4* wsrc = (const f32x4*)(const void*)(WencR + ((size_t)(tile*32)*64 + l)*8);
    #pragma unroll
    for(int kt=0;kt<32;kt++) bw[kt] = wsrc[kt*64];
    #pragma unroll
    for(int kt=0;kt<32;kt++) asm volatile("" : "+v"(bw[kt]));
  }

  float ei0=0,ei1=0,ef0=0,ef1=0,eg0=0,eg1=0,eo0=0,eo1=0;
  if(tid < 256){
    ei0=bhe[hcol];      ei1=bhe[hcol+1];
    ef0=bhe[HH+hcol];   ef1=bhe[HH+hcol+1];
    eg0=bhe[2*HH+hcol]; eg1=bhe[2*HH+hcol+1];
    eo0=bhe[3*HH+hcol]; eo1=bhe[3*HH+hcol+1];
  }

  #pragma unroll 1
  for(int t=0;t<TT;t++){
    {
      const uint4* src = (const uint4*)(h2b + (size_t)(t*BB + bg*16)*EE);
      for(int i = tid; i < 1024; i += 512){
        int r = i >> 6, c16 = i & 63;
        uint4 v = src[r*64 + c16];
        *(uint4*)((char*)Xs + ((r*1024 + c16*16) ^ ((r&7)<<4))) = v;
      }
    }
    __syncthreads();
    f32x4 acc = {0.f,0.f,0.f,0.f};
    {
      const unsigned short* wsrc = WihS + (size_t)tile*16*64*8;
      #pragma unroll
      for(int kt=0;kt<16;kt++){
        bfv8 wf = *(const bfv8*)(const void*)(wsrc + ((size_t)kt*64 + l)*8);
        bfv8 xv = *(const bfv8*)(const void*)((const char*)Xs + ((xbase + kt*64) ^ hswz));
        acc = mfma16(xv, wf, acc);
      }
    }
    g_wait(gen, ge);   // h_t ready
    stage_h(hs, ring + (size_t)(100 + (t&1))*BB*HH, bg, tid);
    __syncthreads();
    #pragma unroll
    for(int kt=0;kt<32;kt++){
      bfv8 hv = *(const bfv8*)(const void*)((const char*)hs + ((hbase + kt*64) ^ hswz));
      acc = mfma16(hv, __builtin_bit_cast(bfv8, bw[kt]), acc);
    }
    {
      int rr = (l>>4)*4;
      #pragma unroll
      for(int q=0;q<4;q++) Gs[rr+q][wvi*16 + fr] = acc[q];
    }
    __syncthreads();
    if(tid < 256){
      float gi0 = Gs[lr][lc]    + ei0, gi1 = Gs[lr][lc+1] + ei1;
      float gf0 = Gs[lr][32+lc] + ef0, gf1 = Gs[lr][33+lc] + ef1;
      float gg0 = Gs[lr][64+lc] + eg0, gg1 = Gs[lr][65+lc] + eg1;
      float go0 = Gs[lr][96+lc] + eo0, go1 = Gs[lr][97+lc] + eo1;
      float c20 = sigm(gf0)*cs0 + sigm(gi0)*tanhf(gg0);
      float c21 = sigm(gf1)*cs1 + sigm(gi1)*tanhf(gg1);
      float h20 = sigm(go0)*tanhf(c20);
      float h21 = sigm(go1)*tanhf(c21);
      if(t < mylen){
        cs0 = c20; cs1 = c21;
        hp = (unsigned)f2b(h20) | ((unsigned)f2b(h21)<<16);
      }
      unsigned short* outslot = (t==TT-1) ? (ring + (size_t)99*BB*HH)
                                          : (ring + (size_t)(100 + ((t+1)&1))*BB*HH);
      __hip_atomic_store((unsigned int*)(outslot + (size_t)(bg*16+lr)*HH + hcol), hp,
                         __ATOMIC_RELAXED, __HIP_MEMORY_SCOPE_AGENT);
    }
    g_arrive(cnt, gen); ge++;
  }

  // ================= decoder: 800 steps =================
  {
    const f32x4* wsrc = (const f32x4*)(const void*)(W2cR + ((size_t)(tile*32)*64 + l)*8);
    #pragma unroll
    for(int kt=0;kt<32;kt++) bw[kt] = wsrc[kt*64];
    #pragma unroll
    for(int kt=0;kt<32;kt++) asm volatile("" : "+v"(bw[kt]));
  }

  float di0=0,di1=0,df0=0,df1=0,dg0=0,dg1=0,do0=0,do1=0;
  if(tid < 256){
    di0=b2[hcol];      di1=b2[hcol+1];
    df0=b2[HH+hcol];   df1=b2[HH+hcol+1];
    dg0=b2[2*HH+hcol]; dg1=b2[2*HH+hcol+1];
    do0=b2[3*HH+hcol]; do1=b2[3*HH+hcol+1];
  }

  #pragma unroll 1
  for(int t=0;t<TMEL;t++){
    g_wait(gen, ge);   // s_t ready
    const unsigned short* slotin = (t==0) ? ring + (size_t)99*BB*HH
                                          : ring + (size_t)((t-1)%100)*BB*HH;
    stage_h(hs, slotin, bg, tid);
    __syncthreads();
    f32x4 acc = {0.f,0.f,0.f,0.f};
    if(t == 0){
      const unsigned short* wsrc = WhhdS + (size_t)tile*32*64*8;
      #pragma unroll
      for(int kt=0;kt<32;kt++){
        bfv8 wf = *(const bfv8*)(const void*)(wsrc + ((size_t)kt*64 + l)*8);
        bfv8 hv = *(const bfv8*)(const void*)((const char*)hs + ((hbase + kt*64) ^ hswz));
        acc = mfma16(hv, wf, acc);
      }
    } else {
      #pragma unroll
      for(int kt=0;kt<32;kt++){
        bfv8 hv = *(const bfv8*)(const void*)((const char*)hs + ((hbase + kt*64) ^ hswz));
        acc = mfma16(hv, __builtin_bit_cast(bfv8, bw[kt]), acc);
      }
    }
    {
      int rr = (l>>4)*4;
      #pragma unroll
      for(int q=0;q<4;q++) Gs[rr+q][wvi*16 + fr] = acc[q];
    }
    __syncthreads();
    if(tid < 256){
      float bi0=di0,bi1=di1,bf0=df0,bf1=df1,bg0=dg0,bg1=dg1,bo0=do0,bo1=do1;
      if(t==0){
        bi0=bd[hcol];      bi1=bd[hcol+1];
        bf0=bd[HH+hcol];   bf1=bd[HH+hcol+1];
        bg0=bd[2*HH+hcol]; bg1=bd[2*HH+hcol+1];
        bo0=bd[3*HH+hcol]; bo1=bd[3*HH+hcol+1];
      }
      float gi0 = Gs[lr][lc]    + bi0, gi1 = Gs[lr][lc+1] + bi1;
      float gf0 = Gs[lr][32+lc] + bf0, gf1 = Gs[lr][33+lc] + bf1;
      float gg0 = Gs[lr][64+lc] + bg0, gg1 = Gs[lr][65+lc] + bg1;
      float go0 = Gs[lr][96+lc] + bo0, go1 = Gs[lr][97+lc] + bo1;
      float c20 = sigm(gf0)*cs0 + sigm(gi0)*tanhf(gg0);
      float c21 = sigm(gf1)*cs1 + sigm(gi1)*tanhf(gg1);
      cs0 = c20; cs1 = c21;
      float h20 = sigm(go0)*tanhf(c20);
      float h21 = sigm(go1)*tanhf(c21);
      unsigned int hn = (unsigned)f2b(h20) | ((unsigned)f2b(h21)<<16);
      unsigned short* outslot = ring + (size_t)(t%100)*BB*HH;
      __hip_atomic_store((unsigned int*)(outslot + (size_t)(bg*16+lr)*HH + hcol), hn,
                         __ATOMIC_RELAXED, __HIP_MEMORY_SCOPE_AGENT);
    }
    g_arrive(cnt, gen); ge++;

    if((t%100)==99){
      g_wait(gen, ge);   // all 100 slots final
      int tbase = t - 99;
      #pragma unroll 1
      for(int s = cg; s < 100; s += 32){
        stage_h(hs, ring + (size_t)s*BB*HH, bg, tid);
        __syncthreads();
        int tout = tbase + s;
        #pragma unroll 1
        for(int pass=0; pass<2; pass++){
          int nt = (pass==0) ? wvi : 8;
          if(pass==1 && wvi!=0) break;
          const unsigned short* wsrc = WpgS + (size_t)nt*32*64*8;
          f32x4 acc = {0.f,0.f,0.f,0.f};
          #pragma unroll
          for(int kt=0;kt<32;kt++){
            bfv8 wf = *(const bfv8*)(const void*)(wsrc + ((size_t)kt*64 + l)*8);
            bfv8 hv = *(const bfv8*)(const void*)((const char*)hs + ((hbase + kt*64) ^ hswz));
            acc = mfma16(hv, wf, acc);
          }
          int n = nt*16 + fr;
          #pragma unroll
          for(int q=0;q<4;q++){
            int b = bg*16 + (l>>4)*4 + q;
            bool msk = tout > mlen[b];
            if(n < MELD)
              outmel[((size_t)b*TMEL + tout)*MELD + n] = msk ? 0.f : acc[q]+bp[n];
            else if(n == MELD)
              outgate[(size_t)b*TMEL + tout] = msk ? 1000.f : acc[q]+bgp[0];
          }
        }
        __syncthreads();
      }
      g_arrive(cnt, gen); ge++;
    }
  }
}

__global__ void k_mask(const int* __restrict__ mlen, float* __restrict__ om){
  int idx=blockIdx.x*256+threadIdx.x; if(idx>=BB*TMEL) return;
  int b=idx/TMEL, t=idx%TMEL;
  om[idx] = (t > mlen[b]) ? 1.f : 0.f;
}

extern "C" void kernel_launch(void* const* d_in, const int* in_sizes, int n_in,
                              void* d_out, int out_size, void* d_ws, size_t ws_size,
                              hipStream_t stream){
  (void)in_sizes; (void)n_in; (void)out_size; (void)ws_size;
  const int*   x    = (const int*)d_in[0];
  const int*   tlen = (const int*)d_in[1];
  const int*   mlen = (const int*)d_in[3];
  const float* emb  = (const float*)d_in[4];
  const float* elW  = (const float*)d_in[5];
  const float* elb  = (const float*)d_in[6];
  const float* c1W  = (const float*)d_in[7];
  const float* c1b  = (const float*)d_in[8];
  const float* g1   = (const float*)d_in[9];
  const float* be1  = (const float*)d_in[10];
  const float* c2W  = (const float*)d_in[11];
  const float* c2b  = (const float*)d_in[12];
  const float* g2   = (const float*)d_in[13];
  const float* be2  = (const float*)d_in[14];
  const float* Wihe = (const float*)d_in[15];
  const float* Whhe = (const float*)d_in[16];
  const float* bhe  = (const float*)d_in[17];
  const float* Wihd = (const float*)d_in[18];
  const float* Whhd = (const float*)d_in[19];
  const float* bhd  = (const float*)d_in[20];
  const float* Wp   = (const float*)d_in[21];
  const float* bp   = (const float*)d_in[22];
  const float* Wg   = (const float*)d_in[23];
  const float* bg   = (const float*)d_in[24];

  float* ws = (float*)d_ws;
  float* proj = ws + OFF_PROJ;
  float* T1   = ws + OFF_T1;
  unsigned short* Wr2b = (unsigned short*)(ws + OFF_WR2);
  float* bb1 = ws + OFF_BB1;
  float* bb2 = ws + OFF_BB2;
  float* b2  = ws + OFF_B2;
  float* W2c = ws + OFF_W2C;
  unsigned int* bar = (unsigned int*)(ws + OFF_BAR);
  unsigned short* WencR = (unsigned short*)(ws + OFF_WENCR);
  unsigned short* WihS  = (unsigned short*)(ws + OFF_WIHS);
  unsigned short* W2cR  = (unsigned short*)(ws + OFF_W2CR);
  unsigned short* WhhdS = (unsigned short*)(ws + OFF_WHHDS);
  unsigned short* WpgS  = (unsigned short*)(ws + OFF_WPGS);
  unsigned short* h2b   = (unsigned short*)(ws + OFF_H2B);
  unsigned short* h1pb  = (unsigned short*)(ws + OFF_RING); // conv scratch
  unsigned short* ring  = (unsigned short*)(ws + OFF_RING); // alias after conv2

  float* outmel  = (float*)d_out;
  float* outgate = outmel + (size_t)BB*TMEL*MELD;
  float* outmask = outgate + (size_t)BB*TMEL;

  hipMemsetAsync(bar, 0, 2048, stream);

  k_proj<<<VV,256,0,stream>>>(emb, elW, elb, proj);
  k_t1<<<dim3(VV,3),256,0,stream>>>(proj, c1W, g1, T1);
  k_wr2<<<(EE*3*EE+255)/256,256,0,stream>>>(c2W, g2, Wr2b);
  k_bb<<<2,256,0,stream>>>(c1b,g1,be1,c2b,g2,be2,bb1,bb2);
  k_b2<<<16,256,0,stream>>>(bhd, Wihd, bp, b2);
  k_w2c<<<dim3(4096/8,HH/256),256,0,stream>>>(Whhd, Wihd, Wp, W2c);
  k_pack<<<256,256,0,stream>>>(Whhe, WencR, 32, 1024);
  k_pack<<<256,256,0,stream>>>(Wihe, WihS, 16, 512);
  k_pack<<<256,256,0,stream>>>(W2c,  W2cR, 32, 1024);
  k_pack<<<256,256,0,stream>>>(Whhd, WhhdS, 32, 1024);
  k_pack_pg<<<9,256,0,stream>>>(Wp, Wg, WpgS);
  k_pad<<<256,256,0,stream>>>(h1pb);
  k_conv1<<<65536,256,0,stream>>>(x, T1, bb1, h1pb);
  k_conv2mm<<<dim3(BB,2,32),256,0,stream>>>(h1pb, Wr2b, bb2, h2b);

  void* kargs[] = {
    (void*)&h2b, (void*)&ring, (void*)&WencR, (void*)&WihS, (void*)&W2cR, (void*)&WhhdS,
    (void*)&WpgS, (void*)&bhe, (void*)&bhd, (void*)&b2, (void*)&bp, (void*)&bg,
    (void*)&bar, (void*)&tlen, (void*)&mlen, (void*)&outmel, (void*)&outgate
  };
  hipLaunchCooperativeKernel((void*)k_recur, dim3(256), dim3(512), kargs, 0u, stream);

  k_mask<<<(BB*TMEL+255)/256,256,0,stream>>>(mlen, outmask);
}